// Round 3
// baseline (14545.509 us; speedup 1.0000x reference)
//
#include <hip/hip_runtime.h>
#include <hip/hip_bf16.h>
#include <math.h>

#define M_ROWS 32768   // B*P
#define GB 128         // graphs
#define GP 256         // points per graph

typedef __hip_bfloat16 bf16;

// ---------------------------------------------------------------------------
// fp32 -> bf16 convert
// ---------------------------------------------------------------------------
__global__ __launch_bounds__(256) void f2b_kernel(const float* __restrict__ in,
                                                  bf16* __restrict__ out, int n)
{
    int i = blockIdx.x * 256 + threadIdx.x;
    if (i < n) out[i] = __float2bfloat16(in[i]);
}

// ---------------------------------------------------------------------------
// GEMM:  C[M,N] = relu?( [A1|A2] @ W + bias (+ C if doAcc) )
// A1:[M,F1] bf16, A2:[M,F2] bf16 (may be null), W:[F1+F2, N] f32 row-major.
// Math fp32 (A converted on load). Output f32 or bf16 (outBf16).
// Tiles: 64x64, BK=16, 256 threads, 4x4 per thread.
// ---------------------------------------------------------------------------
__global__ __launch_bounds__(256) void gemm2(
    const bf16* __restrict__ A1, int F1,
    const bf16* __restrict__ A2, int F2,
    const float* __restrict__ W,
    const float* __restrict__ bias,   // may be null
    void* __restrict__ Cv, int N,
    int doRelu, int doAcc, int outBf16)
{
    __shared__ float As[16][68];   // [k][m]
    __shared__ float Bs[16][64];   // [k][n]
    const int K = F1 + F2;
    const int tid = threadIdx.x;
    const int tx = tid & 15, ty = tid >> 4;
    const int rowBase = blockIdx.x * 64;
    const int colBase = blockIdx.y * 64;
    float acc[4][4] = {};

    for (int k0 = 0; k0 < K; k0 += 16) {
        // A tile: 64 rows x 16 k
        #pragma unroll
        for (int l = 0; l < 4; ++l) {
            int lin = tid + l * 256;
            int r  = lin >> 4;      // 0..63
            int kk = lin & 15;      // 0..15
            int col = k0 + kk;
            float v = 0.f;
            if (col < K) {
                int grow = rowBase + r;
                v = (col < F1) ? __bfloat162float(A1[(size_t)grow * F1 + col])
                               : __bfloat162float(A2[(size_t)grow * F2 + (col - F1)]);
            }
            As[kk][r] = v;
        }
        // W tile: 16 k x 64 n
        #pragma unroll
        for (int l = 0; l < 4; ++l) {
            int lin = tid + l * 256;
            int c  = lin & 63;
            int kk = lin >> 6;
            int col = colBase + c;
            int krow = k0 + kk;
            float v = 0.f;
            if (krow < K && col < N) v = W[(size_t)krow * N + col];
            Bs[kk][c] = v;
        }
        __syncthreads();
        #pragma unroll
        for (int k = 0; k < 16; ++k) {
            float a[4], b[4];
            #pragma unroll
            for (int i = 0; i < 4; ++i) a[i] = As[k][ty * 4 + i];
            #pragma unroll
            for (int j = 0; j < 4; ++j) b[j] = Bs[k][tx * 4 + j];
            #pragma unroll
            for (int i = 0; i < 4; ++i)
                #pragma unroll
                for (int j = 0; j < 4; ++j)
                    acc[i][j] += a[i] * b[j];
        }
        __syncthreads();
    }

    #pragma unroll
    for (int i = 0; i < 4; ++i) {
        int r = rowBase + ty * 4 + i;
        #pragma unroll
        for (int j = 0; j < 4; ++j) {
            int c = colBase + tx * 4 + j;
            if (c < N) {
                float v = acc[i][j];
                if (bias) v += bias[c];
                size_t off = (size_t)r * N + c;
                if (doAcc) v += ((float*)Cv)[off];
                if (doRelu) v = fmaxf(v, 0.f);
                if (outBf16) ((bf16*)Cv)[off] = __float2bfloat16(v);
                else         ((float*)Cv)[off] = v;
            }
        }
    }
}

// ---------------------------------------------------------------------------
// kNN: per graph (block), 256 threads = 1 point each. Top-20 smallest d2 with
// lower-index tie preference (matches jax.lax.top_k on -d2). Emits idx + w.
// ---------------------------------------------------------------------------
__global__ __launch_bounds__(256) void knn_kernel(
    const float* __restrict__ s,   // [B*P, 4]
    int* __restrict__ idx,         // [B*P, 20]
    float* __restrict__ wgt)       // [B*P, 20]
{
    __shared__ float ss[GP][4];
    __shared__ float sq[GP];
    const int b = blockIdx.x;
    const int p = threadIdx.x;
    const float4 v = ((const float4*)(s + (size_t)b * GP * 4))[p];
    ss[p][0] = v.x; ss[p][1] = v.y; ss[p][2] = v.z; ss[p][3] = v.w;
    sq[p] = v.x * v.x + v.y * v.y + v.z * v.z + v.w * v.w;
    __syncthreads();

    float d[20]; int id[20];
    #pragma unroll
    for (int k = 0; k < 20; ++k) { d[k] = 3.402823466e38f; id[k] = -1; }
    const float px = v.x, py = v.y, pz = v.z, pw = v.w;
    const float psq = sq[p];

    for (int q = 0; q < GP; ++q) {
        float dot = px * ss[q][0] + py * ss[q][1] + pz * ss[q][2] + pw * ss[q][3];
        float d2 = psq + sq[q] - 2.f * dot;
        if (d2 < d[19]) {
            #pragma unroll
            for (int i = 19; i > 0; --i) {
                if (d2 < d[i - 1])      { d[i] = d[i - 1]; id[i] = id[i - 1]; }
                else if (d2 < d[i])     { d[i] = d2;       id[i] = q; }
            }
            if (d2 < d[0]) { d[0] = d2; id[0] = q; }
        }
    }
    size_t base = ((size_t)b * GP + p) * 20;
    #pragma unroll
    for (int k = 0; k < 20; ++k) {
        idx[base + k] = id[k];
        wgt[base + k] = expf(-10.f * fmaxf(d[k], 0.f));
    }
}

// ---------------------------------------------------------------------------
// Gather + aggregate: agg[p] = [ mean_k(w*h[idx]), max_k(w*h[idx]) ]  (64+64)
// 256 threads = 4 points x 64 features. h fp32 in, agg bf16 out.
// ---------------------------------------------------------------------------
__global__ __launch_bounds__(256) void gather_kernel(
    const float* __restrict__ h,    // [B*P, 64]
    const int* __restrict__ idx,    // [B*P, 20]
    const float* __restrict__ wgt,  // [B*P, 20]
    bf16* __restrict__ agg)         // [B*P, 128]
{
    const int t = threadIdx.x;
    const int f = t & 63;
    const int lp = t >> 6;
    const int pt = blockIdx.x * 4 + lp;       // global point id
    const int b = pt >> 8;
    const size_t base = (size_t)pt * 20;
    float sum = 0.f, mx = -3.402823466e38f;
    for (int k = 0; k < 20; ++k) {
        int q = idx[base + k];
        float w = wgt[base + k];
        float val = h[(((size_t)b << 8) + q) * 64 + f] * w;
        sum += val;
        mx = fmaxf(mx, val);
    }
    bf16* out = agg + (size_t)pt * 128;
    out[f] = __float2bfloat16(sum * (1.f / 20.f));
    out[64 + f] = __float2bfloat16(mx);
}

// ---------------------------------------------------------------------------
// mid init: mid[m, c] = b_mid[c]
// ---------------------------------------------------------------------------
__global__ __launch_bounds__(256) void init_mid(float* __restrict__ mid,
                                                const float* __restrict__ b_mid)
{
    size_t i = (size_t)blockIdx.x * 256 + threadIdx.x;
    mid[i] = b_mid[i & 511];
}

// ---------------------------------------------------------------------------
// Multi-pool over P=256 rows for a 32-column chunk of mid.
// Order: min, max, mean, sum, std, median (PyG 'lower').
// grid (B, 16), 256 threads.
// ---------------------------------------------------------------------------
__global__ __launch_bounds__(256) void pool_kernel(
    const float* __restrict__ mid,   // [B*P, 512]
    float* __restrict__ pooled)      // [B, 3072]
{
    __shared__ float tile[GP][33];
    __shared__ float rbuf[256];
    const int b = blockIdx.x;
    const int c0 = blockIdx.y * 32;
    const int t = threadIdx.x;

    #pragma unroll 8
    for (int l = 0; l < 32; ++l) {
        int lin = l * 256 + t;
        int row = lin >> 5;
        int col = lin & 31;
        tile[row][col] = mid[((size_t)b * GP + row) * 512 + c0 + col];
    }
    __syncthreads();

    const int col = t & 31, g = t >> 5;    // 8 groups of 32 rows
    float mn = 3.402823466e38f, mx = -3.402823466e38f, sm = 0.f, s2 = 0.f;
    for (int r = g * 32; r < g * 32 + 32; ++r) {
        float v = tile[r][col];
        mn = fminf(mn, v); mx = fmaxf(mx, v); sm += v; s2 += v * v;
    }
    float* outb = pooled + (size_t)b * 3072 + c0;

    rbuf[t] = mn; __syncthreads();
    if (t < 32) {
        float v = rbuf[t];
        #pragma unroll
        for (int k = 1; k < 8; ++k) v = fminf(v, rbuf[t + 32 * k]);
        outb[0 * 512 + t] = v;
    }
    __syncthreads();
    rbuf[t] = mx; __syncthreads();
    if (t < 32) {
        float v = rbuf[t];
        #pragma unroll
        for (int k = 1; k < 8; ++k) v = fmaxf(v, rbuf[t + 32 * k]);
        outb[1 * 512 + t] = v;
    }
    __syncthreads();
    rbuf[t] = sm; __syncthreads();
    float meanv = 0.f;
    if (t < 32) {
        float v = 0.f;
        #pragma unroll
        for (int k = 0; k < 8; ++k) v += rbuf[t + 32 * k];
        meanv = v * (1.f / 256.f);
        outb[2 * 512 + t] = meanv;
        outb[3 * 512 + t] = v;
    }
    __syncthreads();
    rbuf[t] = s2; __syncthreads();
    if (t < 32) {
        float v = 0.f;
        #pragma unroll
        for (int k = 0; k < 8; ++k) v += rbuf[t + 32 * k];
        float var = v * (1.f / 256.f) - meanv * meanv;
        outb[4 * 512 + t] = sqrtf(fmaxf(var, 0.f) + 1e-5f);
    }
    __syncthreads();

    // median: stable rank via counting; thread t owns row t
    for (int c = 0; c < 32; ++c) {
        float v = tile[t][c];
        int cnt = 0;
        for (int j = 0; j < GP; ++j) {
            float u = tile[j][c];
            cnt += (u < v) || (u == v && j < t);
        }
        if (cnt == 127) outb[5 * 512 + c] = v;
    }
}

// ---------------------------------------------------------------------------
// Head: out[b, n] = pooled[b, :] @ W_head[:, n] + b_head[n]
// ---------------------------------------------------------------------------
__global__ __launch_bounds__(128) void head_kernel(
    const float* __restrict__ pooled,  // [B, 3072]
    const float* __restrict__ Wh,      // [3072, 128]
    const float* __restrict__ bh,      // [128]
    float* __restrict__ out)           // [B, 128]
{
    __shared__ float sh[3072];
    const int b = blockIdx.x, t = threadIdx.x;
    for (int l = t; l < 3072; l += 128) sh[l] = pooled[(size_t)b * 3072 + l];
    __syncthreads();
    float acc = bh[t];
    for (int k = 0; k < 3072; ++k) acc += sh[k] * Wh[(size_t)k * 128 + t];
    out[(size_t)b * 128 + t] = acc;
}

// ---------------------------------------------------------------------------
extern "C" void kernel_launch(void* const* d_in, const int* in_sizes, int n_in,
                              void* d_out, int out_size, void* d_ws, size_t ws_size,
                              hipStream_t stream)
{
    const int fi_arr[8] = {8, 256, 256, 512, 512, 512, 1024, 1024};
    const int fo_arr[8] = {256, 256, 512, 512, 512, 1024, 1024, 1024};

    const float* x      = (const float*)d_in[0];
    const float* W_mid  = (const float*)d_in[50];
    const float* b_mid  = (const float*)d_in[51];
    const float* W_head = (const float*)d_in[52];
    const float* b_head = (const float*)d_in[53];

    const size_t M = M_ROWS;

    // ---- workspace layout (fp32 buffers first, then bf16; all 16B aligned)
    float* mid    = (float*)d_ws;            // M*512 f32      = 64 MiB
    float* sbuf   = mid + M * 512;           // M*4 f32        = 0.5 MiB
    float* hbuf   = sbuf + M * 4;            // M*64 f32       = 8 MiB
    float* pooled = hbuf + M * 64;           // 128*3072 f32   = 1.5 MiB
    float* wgtb   = pooled + 128 * 3072;     // M*20 f32       = 2.5 MiB
    int*   idxb   = (int*)(wgtb + M * 20);   // M*20 i32       = 2.5 MiB
    bf16*  xA     = (bf16*)(idxb + M * 20);  // M*1024 bf16    = 64 MiB
    bf16*  xB     = xA + M * 1024;           // M*1024 bf16    = 64 MiB
    bf16*  aggb   = xB + M * 1024;           // M*128 bf16     = 8 MiB
    bf16*  x0b    = aggb + M * 128;          // M*8 bf16       = 0.5 MiB
    size_t needed = (size_t)((char*)(x0b + M * 8) - (char*)d_ws);
    if (ws_size < needed) return;  // diagnostic: clean absmax-fail, no OOB crash

    // x -> bf16
    f2b_kernel<<<(M * 8 + 255) / 256, 256, 0, stream>>>(x, x0b, (int)(M * 8));

    // mid = b_mid, then mid += x0 @ W_mid[0:8]
    init_mid<<<(M * 512) / 256, 256, 0, stream>>>(mid, b_mid);
    gemm2<<<dim3(M / 64, 8), 256, 0, stream>>>(x0b, 8, nullptr, 0,
                                               W_mid, nullptr, mid, 512, 0, 1, 0);
    int mid_off = 8;

    const bf16* xcur = x0b;
    bf16* bufs[2] = {xA, xB};

    for (int L = 0; L < 8; ++L) {
        const int fi = fi_arr[L], fo = fo_arr[L];
        const float* Ws = (const float*)d_in[2 + 6 * L];
        const float* bs = (const float*)d_in[3 + 6 * L];
        const float* Wh = (const float*)d_in[4 + 6 * L];
        const float* bh = (const float*)d_in[5 + 6 * L];
        const float* Wo = (const float*)d_in[6 + 6 * L];
        const float* bo = (const float*)d_in[7 + 6 * L];

        // s = x @ Ws + bs   [M,4] f32
        gemm2<<<dim3(M / 64, 1), 256, 0, stream>>>(xcur, fi, nullptr, 0,
                                                   Ws, bs, sbuf, 4, 0, 0, 0);
        // h = x @ Wh + bh   [M,64] f32
        gemm2<<<dim3(M / 64, 1), 256, 0, stream>>>(xcur, fi, nullptr, 0,
                                                   Wh, bh, hbuf, 64, 0, 0, 0);
        // kNN in s-space
        knn_kernel<<<GB, 256, 0, stream>>>(sbuf, idxb, wgtb);
        // aggregate neighbors -> bf16 agg
        gather_kernel<<<M / 4, 256, 0, stream>>>(hbuf, idxb, wgtb, aggb);
        // x_next = relu([x|agg] @ Wo + bo)  -> bf16
        bf16* xn = bufs[L & 1];
        gemm2<<<dim3(M / 64, fo / 64), 256, 0, stream>>>(xcur, fi, aggb, 128,
                                                         Wo, bo, xn, fo, 1, 0, 1);
        // mid += x_next @ W_mid[mid_off : mid_off+fo]
        gemm2<<<dim3(M / 64, 8), 256, 0, stream>>>(xn, fo, nullptr, 0,
                                                   W_mid + (size_t)mid_off * 512,
                                                   nullptr, mid, 512, 0, 1, 0);
        mid_off += fo;
        xcur = xn;
    }

    // multi-pool (min,max,mean,sum,std,median) -> [B, 3072]
    pool_kernel<<<dim3(GB, 16), 256, 0, stream>>>(mid, pooled);
    // head
    head_kernel<<<GB, 128, 0, stream>>>(pooled, W_head, b_head, (float*)d_out);
}

// Round 4
// 3573.905 us; speedup vs baseline: 4.0699x; 4.0699x over previous
//
#include <hip/hip_runtime.h>
#include <hip/hip_bf16.h>
#include <math.h>

#define M_ROWS 32768   // B*P
#define GB 128         // graphs
#define GP 256         // points per graph

typedef __hip_bfloat16 bf16;
typedef __attribute__((ext_vector_type(8))) short short8;
typedef __attribute__((ext_vector_type(4))) float f32x4;

// ---------------------------------------------------------------------------
// diag: if workspace too small, report ws_size via out[0] (absmax ~ ws_size)
// ---------------------------------------------------------------------------
__global__ void diag_kernel(float* out, float v) { out[0] = v; }

// ---------------------------------------------------------------------------
// MFMA GEMM: C[M,128*gy] = [A @ Wt^T]  with Wt = W^T stored [N, K] bf16.
// BM=128, BN=128, BK=64, 256 threads = 4 waves (2x2), 16x16x32 bf16 MFMA.
// LDS XOR-swizzled (slot ^= row&7) to kill ds_read_b128 bank conflicts (T2).
// MODE 0: sh-combined: cols<64 -> hbuf bf16 [M,64]; cols 64..71 -> sbuf f32 [M,8]
// MODE 1: out bf16 [M,ldc], bias+relu
// MODE 2: out f32 [M,ldc] +=  (accumulate, no bias)
// ---------------------------------------------------------------------------
template<int MODE>
__global__ __launch_bounds__(256) void mgemm(
    const bf16* __restrict__ A, int lda,      // [M, lda] bf16 row-major
    const bf16* __restrict__ Wt,              // [N, K] bf16 (W^T) row-major
    const float* __restrict__ bias,           // [N] f32 or null (MODE2)
    float* __restrict__ out0, int ldc,
    float* __restrict__ out1,                 // MODE0: sbuf
    int K)
{
    __shared__ unsigned short Alds[128][64];
    __shared__ unsigned short Blds[128][64];
    const int tid = threadIdx.x;
    const int l = tid & 63;
    const int w = tid >> 6;
    const int wr = w >> 1, wc = w & 1;
    const int rowBase = blockIdx.x * 128;
    const int colBase = blockIdx.y * 128;

    // staging: id = j*256+tid -> row = j*32 + (tid>>3), 16B-slot = tid&7
    const int strow = tid >> 3;     // 0..31
    const int stcs  = tid & 7;      // 0..7
    const int wslot = (stcs ^ (strow & 7)) * 8;   // swizzled LDS write slot

    const bf16* Ag = A  + (size_t)rowBase * lda + stcs * 8;
    const bf16* Bg = Wt + (size_t)colBase * K   + stcs * 8;

    f32x4 acc[4][4];
    #pragma unroll
    for (int m = 0; m < 4; ++m)
        #pragma unroll
        for (int n = 0; n < 4; ++n)
            acc[m][n] = (f32x4){0.f, 0.f, 0.f, 0.f};

    short8 ra[4], rb[4];
    #pragma unroll
    for (int j = 0; j < 4; ++j) {
        int r = j * 32 + strow;
        ra[j] = *(const short8*)(Ag + (size_t)r * lda);
        rb[j] = *(const short8*)(Bg + (size_t)r * K);
    }

    const int nt = K >> 6;
    for (int t = 0; t < nt; ++t) {
        __syncthreads();   // prior tile's frag reads done
        #pragma unroll
        for (int j = 0; j < 4; ++j) {
            int r = j * 32 + strow;
            *(short8*)&Alds[r][wslot] = ra[j];
            *(short8*)&Blds[r][wslot] = rb[j];
        }
        __syncthreads();
        if (t + 1 < nt) {   // prefetch next tile; latency hides under MFMA
            int kn = (t + 1) << 6;
            #pragma unroll
            for (int j = 0; j < 4; ++j) {
                int r = j * 32 + strow;
                ra[j] = *(const short8*)(Ag + (size_t)r * lda + kn);
                rb[j] = *(const short8*)(Bg + (size_t)r * K + kn);
            }
        }
        #pragma unroll
        for (int kk = 0; kk < 2; ++kk) {
            const int rslot = ((kk * 4 + (l >> 4)) ^ (l & 7)) * 8;
            short8 a[4], b[4];
            #pragma unroll
            for (int m = 0; m < 4; ++m)
                a[m] = *(const short8*)&Alds[wr * 64 + m * 16 + (l & 15)][rslot];
            #pragma unroll
            for (int n = 0; n < 4; ++n)
                b[n] = *(const short8*)&Blds[wc * 64 + n * 16 + (l & 15)][rslot];
            #pragma unroll
            for (int m = 0; m < 4; ++m)
                #pragma unroll
                for (int n = 0; n < 4; ++n)
                    acc[m][n] = __builtin_amdgcn_mfma_f32_16x16x32_bf16(
                        a[m], b[n], acc[m][n], 0, 0, 0);
        }
    }

    // epilogue: C/D layout col=lane&15, row=(lane>>4)*4+reg  [m89/m91]
    const int r0 = rowBase + wr * 64 + (l >> 4) * 4;
    const int c0 = colBase + wc * 64 + (l & 15);
    #pragma unroll
    for (int m = 0; m < 4; ++m) {
        #pragma unroll
        for (int n = 0; n < 4; ++n) {
            const int col = c0 + n * 16;
            const float bv = (MODE == 2) ? 0.f : bias[col];
            #pragma unroll
            for (int g = 0; g < 4; ++g) {
                const int row = r0 + m * 16 + g;
                float v = acc[m][n][g] + bv;
                if (MODE == 0) {
                    if (col < 64)
                        ((bf16*)out0)[(size_t)row * 64 + col] = __float2bfloat16(v);
                    else if (col < 72)
                        out1[(size_t)row * 8 + (col - 64)] = v;
                } else if (MODE == 1) {
                    ((bf16*)out0)[(size_t)row * ldc + col] =
                        __float2bfloat16(fmaxf(v, 0.f));
                } else {
                    out0[(size_t)row * ldc + col] += v;
                }
            }
        }
    }
}

// ---------------------------------------------------------------------------
// Weight prep: transpose-convert W[K,N] f32 -> Wt[N,Kpad] bf16, zero-pad K.
// LDS-tiled 32x32, block (32,8), grid (Kpad/32, N/32).
// ---------------------------------------------------------------------------
__global__ __launch_bounds__(256) void wprep_t(
    const float* __restrict__ W, bf16* __restrict__ Wt,
    int K, int N, int Kpad)
{
    __shared__ float tl[32][33];
    const int tx = threadIdx.x, ty = threadIdx.y;
    const int k_t = blockIdx.x * 32, n_t = blockIdx.y * 32;
    #pragma unroll
    for (int j = 0; j < 4; ++j) {
        int k = k_t + ty + j * 8;
        tl[ty + j * 8][tx] = (k < K) ? W[(size_t)k * N + n_t + tx] : 0.f;
    }
    __syncthreads();
    #pragma unroll
    for (int j = 0; j < 4; ++j) {
        int n = n_t + ty + j * 8;
        Wt[(size_t)n * Kpad + k_t + tx] = __float2bfloat16(tl[tx][ty + j * 8]);
    }
}

// ---------------------------------------------------------------------------
// Build W_sh^T [128, Khpad]: rows 0..63 = Wh^T (bf16); rows 64..67 = hi(Ws^T);
// rows 68..71 = lo(Ws^T) (split-bf16 keeps s effectively fp32); rest 0.
// grid ((Khpad+255)/256, 128), block 256.
// ---------------------------------------------------------------------------
__global__ __launch_bounds__(256) void wprep_sh(
    const float* __restrict__ Wh,   // [fi, 64]
    const float* __restrict__ Ws,   // [fi, 4]
    bf16* __restrict__ Wt,          // [128, Khpad]
    int fi, int Khpad)
{
    const int k = blockIdx.x * 256 + threadIdx.x;
    const int n = blockIdx.y;
    if (k >= Khpad) return;
    float v = 0.f;
    if (k < fi) {
        if (n < 64) v = Wh[(size_t)k * 64 + n];
        else if (n < 68) {
            v = __bfloat162float(__float2bfloat16(Ws[(size_t)k * 4 + (n - 64)]));
        } else if (n < 72) {
            float wv = Ws[(size_t)k * 4 + (n - 68)];
            float hi = __bfloat162float(__float2bfloat16(wv));
            v = wv - hi;
        }
    }
    Wt[(size_t)n * Khpad + k] = __float2bfloat16(v);
}

__global__ __launch_bounds__(128) void bias_build(
    const float* __restrict__ bh, const float* __restrict__ bs,
    float* __restrict__ out)
{
    int t = threadIdx.x;
    out[t] = (t < 64) ? bh[t] : (t < 68 ? bs[t - 64] : 0.f);
}

// ---------------------------------------------------------------------------
// x f32 [M,8] -> x0 buffer bf16 cols 0..8, row stride 192
// ---------------------------------------------------------------------------
__global__ __launch_bounds__(256) void f2b_pad(const float* __restrict__ in,
                                               bf16* __restrict__ out)
{
    int i = blockIdx.x * 256 + threadIdx.x;
    int row = i >> 3, c = i & 7;
    out[(size_t)row * 192 + c] = __float2bfloat16(in[i]);
}

// ---------------------------------------------------------------------------
// kNN: per graph, 256 threads = 1 point. s[c] = sbuf[p*8+c] + sbuf[p*8+4+c]
// (hi+lo split recombine). Top-20 smallest d2, stable (lower-index ties).
// ---------------------------------------------------------------------------
__global__ __launch_bounds__(256) void knn_kernel(
    const float* __restrict__ sbuf,   // [B*P, 8]
    int* __restrict__ idx,            // [B*P, 20]
    float* __restrict__ wgt)          // [B*P, 20]
{
    __shared__ float ss[GP][4];
    __shared__ float sq[GP];
    const int b = blockIdx.x;
    const int p = threadIdx.x;
    const float4 v1 = ((const float4*)(sbuf + ((size_t)b * GP + p) * 8))[0];
    const float4 v2 = ((const float4*)(sbuf + ((size_t)b * GP + p) * 8))[1];
    const float px = v1.x + v2.x, py = v1.y + v2.y,
                pz = v1.z + v2.z, pw = v1.w + v2.w;
    ss[p][0] = px; ss[p][1] = py; ss[p][2] = pz; ss[p][3] = pw;
    sq[p] = px * px + py * py + pz * pz + pw * pw;
    __syncthreads();

    float d[20]; int id[20];
    #pragma unroll
    for (int k = 0; k < 20; ++k) { d[k] = 3.402823466e38f; id[k] = -1; }
    const float psq = sq[p];

    for (int q = 0; q < GP; ++q) {
        float dot = px * ss[q][0] + py * ss[q][1] + pz * ss[q][2] + pw * ss[q][3];
        float d2 = psq + sq[q] - 2.f * dot;
        if (d2 < d[19]) {
            #pragma unroll
            for (int i = 19; i > 0; --i) {
                if (d2 < d[i - 1])      { d[i] = d[i - 1]; id[i] = id[i - 1]; }
                else if (d2 < d[i])     { d[i] = d2;       id[i] = q; }
            }
            if (d2 < d[0]) { d[0] = d2; id[0] = q; }
        }
    }
    size_t base = ((size_t)b * GP + p) * 20;
    #pragma unroll
    for (int k = 0; k < 20; ++k) {
        idx[base + k] = id[k];
        wgt[base + k] = expf(-10.f * fmaxf(d[k], 0.f));
    }
}

// ---------------------------------------------------------------------------
// Gather + aggregate into the activation buffer (inline concat):
// xtgt[pt*stride + fiL + f]      = mean_k(w*h)
// xtgt[pt*stride + fiL + 64 + f] = max_k(w*h)
// padN extra zero cols after agg (L0 only: pad 136..192).
// 256 threads = 4 points x 64 features.
// ---------------------------------------------------------------------------
__global__ __launch_bounds__(256) void gather_kernel(
    const bf16* __restrict__ h,     // [B*P, 64] bf16
    const int* __restrict__ idx,    // [B*P, 20]
    const float* __restrict__ wgt,  // [B*P, 20]
    bf16* __restrict__ xtgt, int stride, int fiL, int padN)
{
    const int t = threadIdx.x;
    const int f = t & 63;
    const int lp = t >> 6;
    const int pt = blockIdx.x * 4 + lp;
    const int b = pt >> 8;
    const size_t base = (size_t)pt * 20;
    float sum = 0.f, mx = -3.402823466e38f;
    for (int k = 0; k < 20; ++k) {
        int q = idx[base + k];
        float wv = wgt[base + k];
        float val = __bfloat162float(h[(((size_t)b << 8) + q) * 64 + f]) * wv;
        sum += val;
        mx = fmaxf(mx, val);
    }
    bf16* out = xtgt + (size_t)pt * stride + fiL;
    out[f] = __float2bfloat16(sum * (1.f / 20.f));
    out[64 + f] = __float2bfloat16(mx);
    if (f < padN) out[128 + f] = __float2bfloat16(0.f);
}

// ---------------------------------------------------------------------------
__global__ __launch_bounds__(256) void init_mid(float* __restrict__ mid,
                                                const float* __restrict__ b_mid)
{
    size_t i = (size_t)blockIdx.x * 256 + threadIdx.x;
    mid[i] = b_mid[i & 511];
}

// ---------------------------------------------------------------------------
// Multi-pool (min,max,mean,sum,std,median-lower) over P=256 rows, 32-col chunk.
// ---------------------------------------------------------------------------
__global__ __launch_bounds__(256) void pool_kernel(
    const float* __restrict__ mid,   // [B*P, 512]
    float* __restrict__ pooled)      // [B, 3072]
{
    __shared__ float tile[GP][33];
    __shared__ float rbuf[256];
    const int b = blockIdx.x;
    const int c0 = blockIdx.y * 32;
    const int t = threadIdx.x;

    #pragma unroll 8
    for (int l = 0; l < 32; ++l) {
        int lin = l * 256 + t;
        int row = lin >> 5;
        int col = lin & 31;
        tile[row][col] = mid[((size_t)b * GP + row) * 512 + c0 + col];
    }
    __syncthreads();

    const int col = t & 31, g = t >> 5;
    float mn = 3.402823466e38f, mx = -3.402823466e38f, sm = 0.f, s2 = 0.f;
    for (int r = g * 32; r < g * 32 + 32; ++r) {
        float v = tile[r][col];
        mn = fminf(mn, v); mx = fmaxf(mx, v); sm += v; s2 += v * v;
    }
    float* outb = pooled + (size_t)b * 3072 + c0;

    rbuf[t] = mn; __syncthreads();
    if (t < 32) {
        float v = rbuf[t];
        #pragma unroll
        for (int k = 1; k < 8; ++k) v = fminf(v, rbuf[t + 32 * k]);
        outb[0 * 512 + t] = v;
    }
    __syncthreads();
    rbuf[t] = mx; __syncthreads();
    if (t < 32) {
        float v = rbuf[t];
        #pragma unroll
        for (int k = 1; k < 8; ++k) v = fmaxf(v, rbuf[t + 32 * k]);
        outb[1 * 512 + t] = v;
    }
    __syncthreads();
    rbuf[t] = sm; __syncthreads();
    float meanv = 0.f;
    if (t < 32) {
        float v = 0.f;
        #pragma unroll
        for (int k = 0; k < 8; ++k) v += rbuf[t + 32 * k];
        meanv = v * (1.f / 256.f);
        outb[2 * 512 + t] = meanv;
        outb[3 * 512 + t] = v;
    }
    __syncthreads();
    rbuf[t] = s2; __syncthreads();
    if (t < 32) {
        float v = 0.f;
        #pragma unroll
        for (int k = 0; k < 8; ++k) v += rbuf[t + 32 * k];
        float var = v * (1.f / 256.f) - meanv * meanv;
        outb[4 * 512 + t] = sqrtf(fmaxf(var, 0.f) + 1e-5f);
    }
    __syncthreads();

    for (int c = 0; c < 32; ++c) {
        float v = tile[t][c];
        int cnt = 0;
        for (int j = 0; j < GP; ++j) {
            float u = tile[j][c];
            cnt += (u < v) || (u == v && j < t);
        }
        if (cnt == 127) outb[5 * 512 + c] = v;
    }
}

// ---------------------------------------------------------------------------
__global__ __launch_bounds__(128) void head_kernel(
    const float* __restrict__ pooled,  // [B, 3072]
    const float* __restrict__ Wh,      // [3072, 128]
    const float* __restrict__ bh,      // [128]
    float* __restrict__ out)           // [B, 128]
{
    __shared__ float sh[3072];
    const int b = blockIdx.x, t = threadIdx.x;
    for (int l = t; l < 3072; l += 128) sh[l] = pooled[(size_t)b * 3072 + l];
    __syncthreads();
    float acc = bh[t];
    for (int k = 0; k < 3072; ++k) acc += sh[k] * Wh[(size_t)k * 128 + t];
    out[(size_t)b * 128 + t] = acc;
}

// ---------------------------------------------------------------------------
extern "C" void kernel_launch(void* const* d_in, const int* in_sizes, int n_in,
                              void* d_out, int out_size, void* d_ws, size_t ws_size,
                              hipStream_t stream)
{
    const int fi[8] = {8, 256, 256, 512, 512, 512, 1024, 1024};
    const int fo[8] = {256, 256, 512, 512, 512, 1024, 1024, 1024};
    const int Kh[8] = {64, 256, 256, 512, 512, 512, 1024, 1024};       // sh-GEMM K (padded)
    const int Ko[8] = {192, 384, 384, 640, 640, 640, 1152, 1152};      // Wo-GEMM K (padded)
    const int Km[9] = {64, 256, 256, 512, 512, 512, 1024, 1024, 1024}; // mid-GEMM K (padded)
    const int Kr[9] = {8, 256, 256, 512, 512, 512, 1024, 1024, 1024};  // real K rows in W_mid
    const int mrow[9] = {0, 8, 264, 520, 1032, 1544, 2056, 3080, 4104};
    const int S[9] = {192, 384, 384, 640, 640, 640, 1152, 1152, 1024}; // activation strides

    const float* x      = (const float*)d_in[0];
    const float* W_mid  = (const float*)d_in[50];
    const float* b_mid  = (const float*)d_in[51];
    const float* W_head = (const float*)d_in[52];
    const float* b_head = (const float*)d_in[53];

    const size_t M = M_ROWS;

    // ---- workspace layout
    char* p = (char*)d_ws;
    float* mid    = (float*)p; p += M * 512 * 4;        // 64 MiB
    float* sbuf   = (float*)p; p += M * 8 * 4;          // 1 MiB
    float* pooled = (float*)p; p += 128 * 3072 * 4;     // 1.5 MiB
    float* wgtb   = (float*)p; p += M * 20 * 4;         // 2.5 MiB
    int*   idxb   = (int*)p;   p += M * 20 * 4;         // 2.5 MiB
    bf16*  hbuf   = (bf16*)p;  p += M * 64 * 2;         // 4 MiB
    bf16*  xA     = (bf16*)p;  p += M * 1152 * 2;       // 75.5 MiB
    bf16*  xB     = (bf16*)p;  p += M * 1152 * 2;       // 75.5 MiB
    float* biassh = (float*)p; p += 8 * 128 * 4;        // 4 KiB
    bf16*  wpool  = (bf16*)p;
    bf16* wsh[8]; bf16* wto[8]; bf16* wtm[9];
    {
        bf16* wp = wpool;
        for (int L = 0; L < 8; ++L) { wsh[L] = wp; wp += (size_t)128 * Kh[L]; }
        for (int L = 0; L < 8; ++L) { wto[L] = wp; wp += (size_t)fo[L] * Ko[L]; }
        for (int i = 0; i < 9; ++i) { wtm[i] = wp; wp += (size_t)512 * Km[i]; }
        p = (char*)wp;
    }
    size_t needed = (size_t)(p - (char*)d_ws);
    if (ws_size < needed) {
        diag_kernel<<<1, 1, 0, stream>>>((float*)d_out, (float)ws_size);
        return;
    }

    // ---- weight prep (per launch; inputs restored each call)
    for (int L = 0; L < 8; ++L) {
        const float* Ws = (const float*)d_in[2 + 6 * L];
        const float* bs = (const float*)d_in[3 + 6 * L];
        const float* Wh = (const float*)d_in[4 + 6 * L];
        const float* bh = (const float*)d_in[5 + 6 * L];
        const float* Wo = (const float*)d_in[6 + 6 * L];
        wprep_sh<<<dim3((Kh[L] + 255) / 256, 128), 256, 0, stream>>>(
            Wh, Ws, wsh[L], fi[L], Kh[L]);
        wprep_t<<<dim3(Ko[L] / 32, fo[L] / 32), dim3(32, 8), 0, stream>>>(
            Wo, wto[L], fi[L] + 128, fo[L], Ko[L]);
        bias_build<<<1, 128, 0, stream>>>(bh, bs, biassh + L * 128);
    }
    for (int i = 0; i < 9; ++i)
        wprep_t<<<dim3(Km[i] / 32, 512 / 32), dim3(32, 8), 0, stream>>>(
            W_mid + (size_t)mrow[i] * 512, wtm[i], Kr[i], 512, Km[i]);

    // ---- forward
    f2b_pad<<<(int)(M * 8 / 256), 256, 0, stream>>>(x, xA);
    init_mid<<<(int)(M * 512 / 256), 256, 0, stream>>>(mid, b_mid);

    bf16* bufs[2] = {xA, xB};
    for (int L = 0; L < 8; ++L) {
        bf16* xin = bufs[L & 1];
        bf16* xout = bufs[(L + 1) & 1];
        const float* bo = (const float*)d_in[7 + 6 * L];

        // h (64 cols, bf16) + s (hi/lo, f32) in one MFMA GEMM
        mgemm<0><<<dim3(256, 1), 256, 0, stream>>>(
            xin, S[L], wsh[L], biassh + L * 128, (float*)hbuf, 64, sbuf, Kh[L]);
        knn_kernel<<<GB, 256, 0, stream>>>(sbuf, idxb, wgtb);
        gather_kernel<<<(int)(M / 4), 256, 0, stream>>>(
            hbuf, idxb, wgtb, xin, S[L], fi[L], (L == 0) ? 56 : 0);
        // mid += x_L @ W_mid[segment L]
        mgemm<2><<<dim3(256, 4), 256, 0, stream>>>(
            xin, S[L], wtm[L], nullptr, mid, 512, nullptr, Km[L]);
        // x_{L+1} = relu([x|agg] @ Wo + bo)
        mgemm<1><<<dim3(256, fo[L] / 128), 256, 0, stream>>>(
            xin, S[L], wto[L], bo, (float*)xout, S[L + 1], nullptr, Ko[L]);
    }
    // final mid segment (x_8)
    mgemm<2><<<dim3(256, 4), 256, 0, stream>>>(
        bufs[0], S[8], wtm[8], nullptr, mid, 512, nullptr, Km[8]);

    pool_kernel<<<dim3(GB, 16), 256, 0, stream>>>(mid, pooled);
    head_kernel<<<GB, 128, 0, stream>>>(pooled, W_head, b_head, (float*)d_out);
}

// Round 5
// 3208.470 us; speedup vs baseline: 4.5335x; 1.1139x over previous
//
#include <hip/hip_runtime.h>
#include <hip/hip_bf16.h>
#include <math.h>

#define M_ROWS 32768   // B*P
#define GB 128         // graphs
#define GP 256         // points per graph

typedef __hip_bfloat16 bf16;
typedef __attribute__((ext_vector_type(8))) short short8;
typedef __attribute__((ext_vector_type(4))) float f32x4;

// ---------------------------------------------------------------------------
__global__ void diag_kernel(float* out, float v) { out[0] = v; }

// ---------------------------------------------------------------------------
// MFMA GEMM, m97 structure: global_load_lds(16B) staging, linear LDS, 2-barrier
// K-loop. BM=128, BN=128, BK=64, 256 threads = 4 waves (2x2), 16x16x32 bf16.
// MODE 0: cols<64 -> hbuf bf16 [M,64]; cols 64..71 -> sbuf f32 [M,8]
// MODE 1: out bf16 [M,ldc], bias+relu
// MODE 2: out f32 [M,ldc] += (accumulate, no bias)
// ---------------------------------------------------------------------------
template<int MODE>
__global__ __launch_bounds__(256) void mgemm(
    const bf16* __restrict__ A, int lda,      // [M, lda] bf16 row-major
    const bf16* __restrict__ Wt,              // [N, K] bf16 (W^T) row-major
    const float* __restrict__ bias,           // [N] f32 or null (MODE2)
    float* __restrict__ out0, int ldc,
    float* __restrict__ out1,                 // MODE0: sbuf
    int K)
{
    __shared__ unsigned short Alds[128][64];  // 16 KiB, linear (gload_lds dest)
    __shared__ unsigned short Blds[128][64];
    const int tid = threadIdx.x;
    const int l = tid & 63;
    const int w = tid >> 6;
    const int wr = w >> 1, wc = w & 1;
    const int rowBase = blockIdx.x * 128;
    const int colBase = blockIdx.y * 128;

    // gload_lds: LDS dest = wave-uniform base + lane*16; global src per-lane.
    // lane l covers tile row (chunk + l>>3), cols (l&7)*8 .. +8
    const int lr = l >> 3;
    const int lc = (l & 7) * 8;
    const bf16* Ab = A  + (size_t)(rowBase + w * 32 + lr) * lda + lc;
    const bf16* Bb = Wt + (size_t)(colBase + w * 32 + lr) * K   + lc;

    f32x4 acc[4][4];
    #pragma unroll
    for (int m = 0; m < 4; ++m)
        #pragma unroll
        for (int n = 0; n < 4; ++n)
            acc[m][n] = (f32x4){0.f, 0.f, 0.f, 0.f};

    const int nt = K >> 6;
    for (int t = 0; t < nt; ++t) {
        const int kt = t << 6;
        __syncthreads();   // prior tile's ds_reads complete before overwrite
        #pragma unroll
        for (int j = 0; j < 4; ++j) {
            __builtin_amdgcn_global_load_lds(
                (const __attribute__((address_space(1))) void*)(Ab + (size_t)(j * 8) * lda + kt),
                (__attribute__((address_space(3))) void*)&Alds[w * 32 + j * 8][0],
                16, 0, 0);
            __builtin_amdgcn_global_load_lds(
                (const __attribute__((address_space(1))) void*)(Bb + (size_t)(j * 8) * K + kt),
                (__attribute__((address_space(3))) void*)&Blds[w * 32 + j * 8][0],
                16, 0, 0);
        }
        __syncthreads();   // drains vmcnt(0) -> tile visible
        #pragma unroll
        for (int kk = 0; kk < 2; ++kk) {
            const int co = kk * 32 + (l >> 4) * 8;
            short8 a[4], b[4];
            #pragma unroll
            for (int m = 0; m < 4; ++m)
                a[m] = *(const short8*)&Alds[wr * 64 + m * 16 + (l & 15)][co];
            #pragma unroll
            for (int n = 0; n < 4; ++n)
                b[n] = *(const short8*)&Blds[wc * 64 + n * 16 + (l & 15)][co];
            #pragma unroll
            for (int m = 0; m < 4; ++m)
                #pragma unroll
                for (int n = 0; n < 4; ++n)
                    acc[m][n] = __builtin_amdgcn_mfma_f32_16x16x32_bf16(
                        a[m], b[n], acc[m][n], 0, 0, 0);
        }
    }

    // epilogue: C/D layout col=lane&15, row=(lane>>4)*4+reg  [m89/m91]
    const int r0 = rowBase + wr * 64 + (l >> 4) * 4;
    const int c0 = colBase + wc * 64 + (l & 15);
    #pragma unroll
    for (int m = 0; m < 4; ++m) {
        #pragma unroll
        for (int n = 0; n < 4; ++n) {
            const int col = c0 + n * 16;
            const float bv = (MODE == 2) ? 0.f : bias[col];
            #pragma unroll
            for (int g = 0; g < 4; ++g) {
                const int row = r0 + m * 16 + g;
                float v = acc[m][n][g] + bv;
                if (MODE == 0) {
                    if (col < 64)
                        ((bf16*)out0)[(size_t)row * 64 + col] = __float2bfloat16(v);
                    else if (col < 72)
                        out1[(size_t)row * 8 + (col - 64)] = v;
                } else if (MODE == 1) {
                    ((bf16*)out0)[(size_t)row * ldc + col] =
                        __float2bfloat16(fmaxf(v, 0.f));
                } else {
                    out0[(size_t)row * ldc + col] += v;
                }
            }
        }
    }
}

// ---------------------------------------------------------------------------
// Weight prep: transpose-convert W[K,N] f32 -> Wt[N,Kpad] bf16, zero-pad K.
// ---------------------------------------------------------------------------
__global__ __launch_bounds__(256) void wprep_t(
    const float* __restrict__ W, bf16* __restrict__ Wt,
    int K, int N, int Kpad)
{
    __shared__ float tl[32][33];
    const int tx = threadIdx.x, ty = threadIdx.y;
    const int k_t = blockIdx.x * 32, n_t = blockIdx.y * 32;
    #pragma unroll
    for (int j = 0; j < 4; ++j) {
        int k = k_t + ty + j * 8;
        tl[ty + j * 8][tx] = (k < K) ? W[(size_t)k * N + n_t + tx] : 0.f;
    }
    __syncthreads();
    #pragma unroll
    for (int j = 0; j < 4; ++j) {
        int n = n_t + ty + j * 8;
        Wt[(size_t)n * Kpad + k_t + tx] = __float2bfloat16(tl[tx][ty + j * 8]);
    }
}

// ---------------------------------------------------------------------------
// Fused prep of all 9 W_mid segments (transpose + zero-pad). grid (162,16).
// ---------------------------------------------------------------------------
__global__ __launch_bounds__(256) void wprep_mid_all(
    const float* __restrict__ W_mid, bf16* __restrict__ wtm0)
{
    const int segBlkStart[10] = {0, 2, 10, 18, 34, 50, 66, 98, 130, 162};
    const int segKm[9]   = {64, 256, 256, 512, 512, 512, 1024, 1024, 1024};
    const int segKr[9]   = {8, 256, 256, 512, 512, 512, 1024, 1024, 1024};
    const int segMrow[9] = {0, 8, 264, 520, 1032, 1544, 2056, 3080, 4104};
    const int segWOff[9] = {0, 32768, 163840, 294912, 557056, 819200,
                            1081344, 1605632, 2129920};
    __shared__ float tl[32][33];
    int bx = blockIdx.x;
    int seg = 0;
    while (bx >= segBlkStart[seg + 1]) ++seg;
    const int kb = bx - segBlkStart[seg];
    const float* W = W_mid + (size_t)segMrow[seg] * 512;
    bf16* Wt = wtm0 + segWOff[seg];
    const int K = segKr[seg], Kpad = segKm[seg];
    const int tx = threadIdx.x, ty = threadIdx.y;
    const int k_t = kb * 32, n_t = blockIdx.y * 32;
    #pragma unroll
    for (int j = 0; j < 4; ++j) {
        int k = k_t + ty + j * 8;
        tl[ty + j * 8][tx] = (k < K) ? W[(size_t)k * 512 + n_t + tx] : 0.f;
    }
    __syncthreads();
    #pragma unroll
    for (int j = 0; j < 4; ++j) {
        int n = n_t + ty + j * 8;
        Wt[(size_t)n * Kpad + k_t + tx] = __float2bfloat16(tl[tx][ty + j * 8]);
    }
}

// ---------------------------------------------------------------------------
// W_sh^T [128, Khpad]: rows 0..63 = Wh^T; 64..67 = hi(Ws^T); 68..71 = lo(Ws^T)
// ---------------------------------------------------------------------------
__global__ __launch_bounds__(256) void wprep_sh(
    const float* __restrict__ Wh,   // [fi, 64]
    const float* __restrict__ Ws,   // [fi, 4]
    bf16* __restrict__ Wt,          // [128, Khpad]
    int fi, int Khpad)
{
    const int k = blockIdx.x * 256 + threadIdx.x;
    const int n = blockIdx.y;
    if (k >= Khpad) return;
    float v = 0.f;
    if (k < fi) {
        if (n < 64) v = Wh[(size_t)k * 64 + n];
        else if (n < 68) {
            v = __bfloat162float(__float2bfloat16(Ws[(size_t)k * 4 + (n - 64)]));
        } else if (n < 72) {
            float wv = Ws[(size_t)k * 4 + (n - 68)];
            float hi = __bfloat162float(__float2bfloat16(wv));
            v = wv - hi;
        }
    }
    Wt[(size_t)n * Khpad + k] = __float2bfloat16(v);
}

struct BiasArgs { const float* bh[8]; const float* bs[8]; };
__global__ __launch_bounds__(128) void bias_build_all(
    BiasArgs a, float* __restrict__ out)
{
    const int L = blockIdx.x, t = threadIdx.x;
    out[L * 128 + t] = (t < 64) ? a.bh[L][t] : (t < 68 ? a.bs[L][t - 64] : 0.f);
}

// ---------------------------------------------------------------------------
__global__ __launch_bounds__(256) void f2b_pad(const float* __restrict__ in,
                                               bf16* __restrict__ out)
{
    int i = blockIdx.x * 256 + threadIdx.x;
    int row = i >> 3, c = i & 7;
    out[(size_t)row * 192 + c] = __float2bfloat16(in[i]);
}

// ---------------------------------------------------------------------------
// kNN: grid (128 graphs, 2 halves), 128 threads = 1 point each.
// s recombined from hi+lo split. Top-20 smallest d2, stable ties.
// ---------------------------------------------------------------------------
__global__ __launch_bounds__(128) void knn_kernel(
    const float* __restrict__ sbuf,   // [B*P, 8]
    int* __restrict__ idx,            // [B*P, 20]
    float* __restrict__ wgt)          // [B*P, 20]
{
    __shared__ float ss[GP][4];
    __shared__ float sq[GP];
    const int b = blockIdx.x;
    const int t = threadIdx.x;
    for (int i = t; i < GP; i += 128) {
        const float4 v1 = ((const float4*)(sbuf + ((size_t)b * GP + i) * 8))[0];
        const float4 v2 = ((const float4*)(sbuf + ((size_t)b * GP + i) * 8))[1];
        const float ax = v1.x + v2.x, ay = v1.y + v2.y,
                    az = v1.z + v2.z, aw = v1.w + v2.w;
        ss[i][0] = ax; ss[i][1] = ay; ss[i][2] = az; ss[i][3] = aw;
        sq[i] = ax * ax + ay * ay + az * az + aw * aw;
    }
    __syncthreads();
    const int p = blockIdx.y * 128 + t;
    const float px = ss[p][0], py = ss[p][1], pz = ss[p][2], pw = ss[p][3];
    const float psq = sq[p];

    float d[20]; int id[20];
    #pragma unroll
    for (int k = 0; k < 20; ++k) { d[k] = 3.402823466e38f; id[k] = -1; }

    for (int q = 0; q < GP; ++q) {
        float dot = px * ss[q][0] + py * ss[q][1] + pz * ss[q][2] + pw * ss[q][3];
        float d2 = psq + sq[q] - 2.f * dot;
        if (d2 < d[19]) {
            #pragma unroll
            for (int i = 19; i > 0; --i) {
                if (d2 < d[i - 1])      { d[i] = d[i - 1]; id[i] = id[i - 1]; }
                else if (d2 < d[i])     { d[i] = d2;       id[i] = q; }
            }
            if (d2 < d[0]) { d[0] = d2; id[0] = q; }
        }
    }
    size_t base = ((size_t)p + (size_t)b * GP - (size_t)t
                   + (size_t)t + (size_t)blockIdx.y * 128) * 20;
    base = ((size_t)b * GP + p) * 20;
    #pragma unroll
    for (int k = 0; k < 20; ++k) {
        idx[base + k] = id[k];
        wgt[base + k] = expf(-10.f * fmaxf(d[k], 0.f));
    }
}

// ---------------------------------------------------------------------------
// Gather + aggregate into the activation buffer (inline concat).
// ---------------------------------------------------------------------------
__global__ __launch_bounds__(256) void gather_kernel(
    const bf16* __restrict__ h,     // [B*P, 64] bf16
    const int* __restrict__ idx,    // [B*P, 20]
    const float* __restrict__ wgt,  // [B*P, 20]
    bf16* __restrict__ xtgt, int stride, int fiL, int padN)
{
    const int t = threadIdx.x;
    const int f = t & 63;
    const int lp = t >> 6;
    const int pt = blockIdx.x * 4 + lp;
    const int b = pt >> 8;
    const size_t base = (size_t)pt * 20;
    float sum = 0.f, mx = -3.402823466e38f;
    for (int k = 0; k < 20; ++k) {
        int q = idx[base + k];
        float wv = wgt[base + k];
        float val = __bfloat162float(h[(((size_t)b << 8) + q) * 64 + f]) * wv;
        sum += val;
        mx = fmaxf(mx, val);
    }
    bf16* out = xtgt + (size_t)pt * stride + fiL;
    out[f] = __float2bfloat16(sum * (1.f / 20.f));
    out[64 + f] = __float2bfloat16(mx);
    if (f < padN) out[128 + f] = __float2bfloat16(0.f);
}

// ---------------------------------------------------------------------------
__global__ __launch_bounds__(256) void init_mid(float* __restrict__ mid,
                                                const float* __restrict__ b_mid)
{
    size_t i = (size_t)blockIdx.x * 256 + threadIdx.x;
    mid[i] = b_mid[i & 511];
}

// ---------------------------------------------------------------------------
// Multi-pool (min,max,mean,sum,std,median-lower). Median via in-LDS bitonic
// sort over 256 rows, vectorized across the 32-col chunk. grid (B,16).
// ---------------------------------------------------------------------------
__global__ __launch_bounds__(256) void pool_kernel(
    const float* __restrict__ mid,   // [B*P, 512]
    float* __restrict__ pooled)      // [B, 3072]
{
    __shared__ float tile[GP][33];
    __shared__ float rbuf[256];
    const int b = blockIdx.x;
    const int c0 = blockIdx.y * 32;
    const int t = threadIdx.x;

    #pragma unroll 8
    for (int l = 0; l < 32; ++l) {
        int lin = l * 256 + t;
        int row = lin >> 5;
        int col = lin & 31;
        tile[row][col] = mid[((size_t)b * GP + row) * 512 + c0 + col];
    }
    __syncthreads();

    const int col = t & 31, g = t >> 5;
    float mn = 3.402823466e38f, mx = -3.402823466e38f, sm = 0.f, s2 = 0.f;
    for (int r = g * 32; r < g * 32 + 32; ++r) {
        float v = tile[r][col];
        mn = fminf(mn, v); mx = fmaxf(mx, v); sm += v; s2 += v * v;
    }
    float* outb = pooled + (size_t)b * 3072 + c0;

    rbuf[t] = mn; __syncthreads();
    if (t < 32) {
        float v = rbuf[t];
        #pragma unroll
        for (int k = 1; k < 8; ++k) v = fminf(v, rbuf[t + 32 * k]);
        outb[0 * 512 + t] = v;
    }
    __syncthreads();
    rbuf[t] = mx; __syncthreads();
    if (t < 32) {
        float v = rbuf[t];
        #pragma unroll
        for (int k = 1; k < 8; ++k) v = fmaxf(v, rbuf[t + 32 * k]);
        outb[1 * 512 + t] = v;
    }
    __syncthreads();
    rbuf[t] = sm; __syncthreads();
    float meanv = 0.f;
    if (t < 32) {
        float v = 0.f;
        #pragma unroll
        for (int k = 0; k < 8; ++k) v += rbuf[t + 32 * k];
        meanv = v * (1.f / 256.f);
        outb[2 * 512 + t] = meanv;
        outb[3 * 512 + t] = v;
    }
    __syncthreads();
    rbuf[t] = s2; __syncthreads();
    if (t < 32) {
        float v = 0.f;
        #pragma unroll
        for (int k = 0; k < 8; ++k) v += rbuf[t + 32 * k];
        float var = v * (1.f / 256.f) - meanv * meanv;
        outb[4 * 512 + t] = sqrtf(fmaxf(var, 0.f) + 1e-5f);
    }

    // ---- median: bitonic sort rows ascending (value multiset -> rank 127)
    for (int size = 2; size <= 256; size <<= 1) {
        for (int stride = size >> 1; stride > 0; stride >>= 1) {
            __syncthreads();
            #pragma unroll
            for (int it = 0; it < 16; ++it) {
                int task = it * 256 + t;        // 4096 = 128 pairs x 32 cols
                int c = task & 31;
                int pp = task >> 5;             // 0..127
                int i = 2 * pp - (pp & (stride - 1));
                int j = i + stride;
                bool up = ((i & size) == 0);
                float va = tile[i][c], vb = tile[j][c];
                bool sw = up ? (va > vb) : (va < vb);
                if (sw) { tile[i][c] = vb; tile[j][c] = va; }
            }
        }
    }
    __syncthreads();
    if (t < 32) outb[5 * 512 + t] = tile[127][t];
}

// ---------------------------------------------------------------------------
__global__ __launch_bounds__(128) void head_kernel(
    const float* __restrict__ pooled,  // [B, 3072]
    const float* __restrict__ Wh,      // [3072, 128]
    const float* __restrict__ bh,      // [128]
    float* __restrict__ out)           // [B, 128]
{
    __shared__ float sh[3072];
    const int b = blockIdx.x, t = threadIdx.x;
    for (int l = t; l < 3072; l += 128) sh[l] = pooled[(size_t)b * 3072 + l];
    __syncthreads();
    float acc = bh[t];
    for (int k = 0; k < 3072; ++k) acc += sh[k] * Wh[(size_t)k * 128 + t];
    out[(size_t)b * 128 + t] = acc;
}

// ---------------------------------------------------------------------------
extern "C" void kernel_launch(void* const* d_in, const int* in_sizes, int n_in,
                              void* d_out, int out_size, void* d_ws, size_t ws_size,
                              hipStream_t stream)
{
    const int fi[8] = {8, 256, 256, 512, 512, 512, 1024, 1024};
    const int fo[8] = {256, 256, 512, 512, 512, 1024, 1024, 1024};
    const int Kh[8] = {64, 256, 256, 512, 512, 512, 1024, 1024};
    const int Ko[8] = {192, 384, 384, 640, 640, 640, 1152, 1152};
    const int Km[9] = {64, 256, 256, 512, 512, 512, 1024, 1024, 1024};
    const int S[9]  = {192, 384, 384, 640, 640, 640, 1152, 1152, 1024};

    const float* x      = (const float*)d_in[0];
    const float* W_mid  = (const float*)d_in[50];
    const float* b_mid  = (const float*)d_in[51];
    const float* W_head = (const float*)d_in[52];
    const float* b_head = (const float*)d_in[53];

    const size_t M = M_ROWS;

    // ---- workspace layout
    char* p = (char*)d_ws;
    float* mid    = (float*)p; p += M * 512 * 4;
    float* sbuf   = (float*)p; p += M * 8 * 4;
    float* pooled = (float*)p; p += 128 * 3072 * 4;
    float* wgtb   = (float*)p; p += M * 20 * 4;
    int*   idxb   = (int*)p;   p += M * 20 * 4;
    bf16*  hbuf   = (bf16*)p;  p += M * 64 * 2;
    bf16*  xA     = (bf16*)p;  p += M * 1152 * 2;
    bf16*  xB     = (bf16*)p;  p += M * 1152 * 2;
    float* biassh = (float*)p; p += 8 * 128 * 4;
    bf16*  wpool  = (bf16*)p;
    bf16* wsh[8]; bf16* wto[8]; bf16* wtm[9];
    {
        bf16* wp = wpool;
        for (int L = 0; L < 8; ++L) { wsh[L] = wp; wp += (size_t)128 * Kh[L]; }
        for (int L = 0; L < 8; ++L) { wto[L] = wp; wp += (size_t)fo[L] * Ko[L]; }
        for (int i = 0; i < 9; ++i) { wtm[i] = wp; wp += (size_t)512 * Km[i]; }
        p = (char*)wp;
    }
    size_t needed = (size_t)(p - (char*)d_ws);
    if (ws_size < needed) {
        diag_kernel<<<1, 1, 0, stream>>>((float*)d_out, (float)ws_size);
        return;
    }

    // ---- weight prep
    BiasArgs ba;
    for (int L = 0; L < 8; ++L) {
        const float* Ws = (const float*)d_in[2 + 6 * L];
        const float* bs = (const float*)d_in[3 + 6 * L];
        const float* Wh = (const float*)d_in[4 + 6 * L];
        const float* bh = (const float*)d_in[5 + 6 * L];
        const float* Wo = (const float*)d_in[6 + 6 * L];
        ba.bh[L] = bh; ba.bs[L] = bs;
        wprep_sh<<<dim3((Kh[L] + 255) / 256, 128), 256, 0, stream>>>(
            Wh, Ws, wsh[L], fi[L], Kh[L]);
        wprep_t<<<dim3(Ko[L] / 32, fo[L] / 32), dim3(32, 8), 0, stream>>>(
            Wo, wto[L], fi[L] + 128, fo[L], Ko[L]);
    }
    bias_build_all<<<8, 128, 0, stream>>>(ba, biassh);
    wprep_mid_all<<<dim3(162, 16), dim3(32, 8), 0, stream>>>(W_mid, wtm[0]);

    // ---- forward
    f2b_pad<<<(int)(M * 8 / 256), 256, 0, stream>>>(x, xA);
    init_mid<<<(int)(M * 512 / 256), 256, 0, stream>>>(mid, b_mid);

    bf16* bufs[2] = {xA, xB};
    for (int L = 0; L < 8; ++L) {
        bf16* xin = bufs[L & 1];
        bf16* xout = bufs[(L + 1) & 1];
        const float* bo = (const float*)d_in[7 + 6 * L];

        mgemm<0><<<dim3(256, 1), 256, 0, stream>>>(
            xin, S[L], wsh[L], biassh + L * 128, (float*)hbuf, 64, sbuf, Kh[L]);
        knn_kernel<<<dim3(GB, 2), 128, 0, stream>>>(sbuf, idxb, wgtb);
        gather_kernel<<<(int)(M / 4), 256, 0, stream>>>(
            hbuf, idxb, wgtb, xin, S[L], fi[L], (L == 0) ? 56 : 0);
        mgemm<2><<<dim3(256, 4), 256, 0, stream>>>(
            xin, S[L], wtm[L], nullptr, mid, 512, nullptr, Km[L]);
        mgemm<1><<<dim3(256, fo[L] / 128), 256, 0, stream>>>(
            xin, S[L], wto[L], bo, (float*)xout, S[L + 1], nullptr, Ko[L]);
    }
    mgemm<2><<<dim3(256, 4), 256, 0, stream>>>(
        bufs[0], S[8], wtm[8], nullptr, mid, 512, nullptr, Km[8]);

    pool_kernel<<<dim3(GB, 16), 256, 0, stream>>>(mid, pooled);
    head_kernel<<<GB, 128, 0, stream>>>(pooled, W_head, b_head, (float*)d_out);
}

// Round 8
// 2171.774 us; speedup vs baseline: 6.6975x; 1.4773x over previous
//
#include <hip/hip_runtime.h>
#include <hip/hip_bf16.h>
#include <math.h>

#define M_ROWS 32768   // B*P
#define GB 128         // graphs
#define GP 256         // points per graph

typedef __hip_bfloat16 bf16;
typedef __attribute__((ext_vector_type(8))) short short8;
typedef __attribute__((ext_vector_type(4))) float f32x4;

// ---------------------------------------------------------------------------
__global__ void diag_kernel(float* out, float v) { out[0] = v; }

// ---------------------------------------------------------------------------
// MFMA GEMM, m97 structure: global_load_lds(16B) staging, linear LDS, 2-barrier
// K-loop. BM=128, BN=128, BK=64, 256 threads = 4 waves (2x2), 16x16x32 bf16.
// MODE 0: cols<64 -> hbuf bf16 [M,64]; cols 64..71 -> sbuf f32 [M,8]
// MODE 1: out bf16 [M,ldc], bias+relu
// MODE 2: out f32 [M,ldc] += (accumulate, no bias)
// ---------------------------------------------------------------------------
template<int MODE>
__global__ __launch_bounds__(256) void mgemm(
    const bf16* __restrict__ A, int lda,      // [M, lda] bf16 row-major
    const bf16* __restrict__ Wt,              // [N, K] bf16 (W^T) row-major
    const float* __restrict__ bias,           // [N] f32 or null (MODE2)
    float* __restrict__ out0, int ldc,
    float* __restrict__ out1,                 // MODE0: sbuf
    int K)
{
    __shared__ unsigned short Alds[128][64];  // 16 KiB, linear (gload_lds dest)
    __shared__ unsigned short Blds[128][64];
    const int tid = threadIdx.x;
    const int l = tid & 63;
    const int w = tid >> 6;
    const int wr = w >> 1, wc = w & 1;
    const int rowBase = blockIdx.x * 128;
    const int colBase = blockIdx.y * 128;

    const int lr = l >> 3;
    const int lc = (l & 7) * 8;
    const bf16* Ab = A  + (size_t)(rowBase + w * 32 + lr) * lda + lc;
    const bf16* Bb = Wt + (size_t)(colBase + w * 32 + lr) * K   + lc;

    f32x4 acc[4][4];
    #pragma unroll
    for (int m = 0; m < 4; ++m)
        #pragma unroll
        for (int n = 0; n < 4; ++n)
            acc[m][n] = (f32x4){0.f, 0.f, 0.f, 0.f};

    const int nt = K >> 6;
    for (int t = 0; t < nt; ++t) {
        const int kt = t << 6;
        __syncthreads();
        #pragma unroll
        for (int j = 0; j < 4; ++j) {
            __builtin_amdgcn_global_load_lds(
                (const __attribute__((address_space(1))) void*)(Ab + (size_t)(j * 8) * lda + kt),
                (__attribute__((address_space(3))) void*)&Alds[w * 32 + j * 8][0],
                16, 0, 0);
            __builtin_amdgcn_global_load_lds(
                (const __attribute__((address_space(1))) void*)(Bb + (size_t)(j * 8) * K + kt),
                (__attribute__((address_space(3))) void*)&Blds[w * 32 + j * 8][0],
                16, 0, 0);
        }
        __syncthreads();
        #pragma unroll
        for (int kk = 0; kk < 2; ++kk) {
            const int co = kk * 32 + (l >> 4) * 8;
            short8 a[4], b[4];
            #pragma unroll
            for (int m = 0; m < 4; ++m)
                a[m] = *(const short8*)&Alds[wr * 64 + m * 16 + (l & 15)][co];
            #pragma unroll
            for (int n = 0; n < 4; ++n)
                b[n] = *(const short8*)&Blds[wc * 64 + n * 16 + (l & 15)][co];
            #pragma unroll
            for (int m = 0; m < 4; ++m)
                #pragma unroll
                for (int n = 0; n < 4; ++n)
                    acc[m][n] = __builtin_amdgcn_mfma_f32_16x16x32_bf16(
                        a[m], b[n], acc[m][n], 0, 0, 0);
        }
    }

    // epilogue: C/D layout col=lane&15, row=(lane>>4)*4+reg  [m89/m91]
    const int r0 = rowBase + wr * 64 + (l >> 4) * 4;
    const int c0 = colBase + wc * 64 + (l & 15);
    #pragma unroll
    for (int m = 0; m < 4; ++m) {
        #pragma unroll
        for (int n = 0; n < 4; ++n) {
            const int col = c0 + n * 16;
            const float bv = (MODE == 2) ? 0.f : bias[col];
            #pragma unroll
            for (int g = 0; g < 4; ++g) {
                const int row = r0 + m * 16 + g;
                float v = acc[m][n][g] + bv;
                if (MODE == 0) {
                    if (col < 64)
                        ((bf16*)out0)[(size_t)row * 64 + col] = __float2bfloat16(v);
                    else if (col < 72)
                        out1[(size_t)row * 8 + (col - 64)] = v;
                } else if (MODE == 1) {
                    ((bf16*)out0)[(size_t)row * ldc + col] =
                        __float2bfloat16(fmaxf(v, 0.f));
                } else {
                    out0[(size_t)row * ldc + col] += v;
                }
            }
        }
    }
}

// ---------------------------------------------------------------------------
__global__ __launch_bounds__(256) void wprep_t(
    const float* __restrict__ W, bf16* __restrict__ Wt,
    int K, int N, int Kpad)
{
    __shared__ float tl[32][33];
    const int tx = threadIdx.x, ty = threadIdx.y;
    const int k_t = blockIdx.x * 32, n_t = blockIdx.y * 32;
    #pragma unroll
    for (int j = 0; j < 4; ++j) {
        int k = k_t + ty + j * 8;
        tl[ty + j * 8][tx] = (k < K) ? W[(size_t)k * N + n_t + tx] : 0.f;
    }
    __syncthreads();
    #pragma unroll
    for (int j = 0; j < 4; ++j) {
        int n = n_t + ty + j * 8;
        Wt[(size_t)n * Kpad + k_t + tx] = __float2bfloat16(tl[tx][ty + j * 8]);
    }
}

// ---------------------------------------------------------------------------
__global__ __launch_bounds__(256) void wprep_mid_all(
    const float* __restrict__ W_mid, bf16* __restrict__ wtm0)
{
    const int segBlkStart[10] = {0, 2, 10, 18, 34, 50, 66, 98, 130, 162};
    const int segKm[9]   = {64, 256, 256, 512, 512, 512, 1024, 1024, 1024};
    const int segKr[9]   = {8, 256, 256, 512, 512, 512, 1024, 1024, 1024};
    const int segMrow[9] = {0, 8, 264, 520, 1032, 1544, 2056, 3080, 4104};
    const int segWOff[9] = {0, 32768, 163840, 294912, 557056, 819200,
                            1081344, 1605632, 2129920};
    __shared__ float tl[32][33];
    int bx = blockIdx.x;
    int seg = 0;
    while (bx >= segBlkStart[seg + 1]) ++seg;
    const int kb = bx - segBlkStart[seg];
    const float* W = W_mid + (size_t)segMrow[seg] * 512;
    bf16* Wt = wtm0 + segWOff[seg];
    const int K = segKr[seg], Kpad = segKm[seg];
    const int tx = threadIdx.x, ty = threadIdx.y;
    const int k_t = kb * 32, n_t = blockIdx.y * 32;
    #pragma unroll
    for (int j = 0; j < 4; ++j) {
        int k = k_t + ty + j * 8;
        tl[ty + j * 8][tx] = (k < K) ? W[(size_t)k * 512 + n_t + tx] : 0.f;
    }
    __syncthreads();
    #pragma unroll
    for (int j = 0; j < 4; ++j) {
        int n = n_t + ty + j * 8;
        Wt[(size_t)n * Kpad + k_t + tx] = __float2bfloat16(tl[tx][ty + j * 8]);
    }
}

// ---------------------------------------------------------------------------
__global__ __launch_bounds__(256) void wprep_sh(
    const float* __restrict__ Wh,   // [fi, 64]
    const float* __restrict__ Ws,   // [fi, 4]
    bf16* __restrict__ Wt,          // [128, Khpad]
    int fi, int Khpad)
{
    const int k = blockIdx.x * 256 + threadIdx.x;
    const int n = blockIdx.y;
    if (k >= Khpad) return;
    float v = 0.f;
    if (k < fi) {
        if (n < 64) v = Wh[(size_t)k * 64 + n];
        else if (n < 68) {
            v = __bfloat162float(__float2bfloat16(Ws[(size_t)k * 4 + (n - 64)]));
        } else if (n < 72) {
            float wv = Ws[(size_t)k * 4 + (n - 68)];
            float hi = __bfloat162float(__float2bfloat16(wv));
            v = wv - hi;
        }
    }
    Wt[(size_t)n * Khpad + k] = __float2bfloat16(v);
}

struct BiasArgs { const float* bh[8]; const float* bs[8]; };
__global__ __launch_bounds__(128) void bias_build_all(
    BiasArgs a, float* __restrict__ out)
{
    const int L = blockIdx.x, t = threadIdx.x;
    out[L * 128 + t] = (t < 64) ? a.bh[L][t] : (t < 68 ? a.bs[L][t - 64] : 0.f);
}

// ---------------------------------------------------------------------------
__global__ __launch_bounds__(256) void f2b_pad(const float* __restrict__ in,
                                               bf16* __restrict__ out)
{
    int i = blockIdx.x * 256 + threadIdx.x;
    int row = i >> 3, c = i & 7;
    out[(size_t)row * 192 + c] = __float2bfloat16(in[i]);
}

// ---------------------------------------------------------------------------
// kNN, wave-per-point: 256 threads = 4 waves = 4 points; grid M/4.
// Lane holds 4 (d,q) pairs in named registers (sorted); 20 extraction steps:
// wave-wide shfl_xor min + ballot-pick-winner + pop. No arrays -> no scratch.
// ss stride 5 words -> 2 lanes/bank on candidate reads (free, m136).
// ---------------------------------------------------------------------------
__global__ __launch_bounds__(256) void knn_kernel(
    const float* __restrict__ sbuf,   // [B*P, 8] (hi/lo split)
    int* __restrict__ idx,            // [B*P, 20]
    float* __restrict__ wgt)          // [B*P, 20]
{
    __shared__ float ss[GP][5];       // [q][0..3]=coords, [4]=|s|^2
    const int t = threadIdx.x;
    const int b = blockIdx.x >> 6;    // 64 blocks per graph
    {
        const float4 v1 = ((const float4*)(sbuf + ((size_t)b * GP + t) * 8))[0];
        const float4 v2 = ((const float4*)(sbuf + ((size_t)b * GP + t) * 8))[1];
        float ax = v1.x + v2.x, ay = v1.y + v2.y,
              az = v1.z + v2.z, aw = v1.w + v2.w;
        ss[t][0] = ax; ss[t][1] = ay; ss[t][2] = az; ss[t][3] = aw;
        ss[t][4] = ax * ax + ay * ay + az * az + aw * aw;
    }
    __syncthreads();

    const int w = t >> 6, l = t & 63;
    const int p = (blockIdx.x * 4 + w) & 255;   // this wave's point (local)
    const float px = ss[p][0], py = ss[p][1], pz = ss[p][2], pq = ss[p][3];
    const float psq = ss[p][4];

    float d0, d1, d2, d3; int q0, q1, q2, q3;
    #define KNN_DIST(DD, QQ, J) { \
        const int q_ = l + (J) * 64; \
        float dot_ = px * ss[q_][0] + py * ss[q_][1] \
                   + pz * ss[q_][2] + pq * ss[q_][3]; \
        DD = psq + ss[q_][4] - 2.f * dot_; QQ = q_; }
    KNN_DIST(d0, q0, 0) KNN_DIST(d1, q1, 1)
    KNN_DIST(d2, q2, 2) KNN_DIST(d3, q3, 3)
    #undef KNN_DIST
    // sort 4 ascending (5-CE network), named scalars only
    #define KNN_CE(DA, DB, QA, QB) { \
        if (DA > DB) { float td = DA; DA = DB; DB = td; \
                       int tq = QA; QA = QB; QB = tq; } }
    KNN_CE(d0, d1, q0, q1) KNN_CE(d2, d3, q2, q3)
    KNN_CE(d0, d2, q0, q2) KNN_CE(d1, d3, q1, q3)
    KNN_CE(d1, d2, q1, q2)
    #undef KNN_CE

    const size_t base = ((size_t)b * GP + p) * 20;
    #pragma unroll
    for (int k = 0; k < 20; ++k) {
        float m = d0;
        #pragma unroll
        for (int off = 32; off; off >>= 1)
            m = fminf(m, __shfl_xor(m, off));
        unsigned long long msk = __ballot(d0 == m);
        int winner = __ffsll((long long)msk) - 1;
        if (l == winner) {
            idx[base + k] = q0;
            wgt[base + k] = expf(-10.f * fmaxf(m, 0.f));
            d0 = d1; q0 = q1; d1 = d2; q1 = q2;
            d2 = d3; q2 = q3; d3 = 3.402823466e38f;
        }
    }
}

// ---------------------------------------------------------------------------
__global__ __launch_bounds__(256) void gather_kernel(
    const bf16* __restrict__ h,     // [B*P, 64] bf16
    const int* __restrict__ idx,    // [B*P, 20]
    const float* __restrict__ wgt,  // [B*P, 20]
    bf16* __restrict__ xtgt, int stride, int fiL, int padN)
{
    const int t = threadIdx.x;
    const int f = t & 63;
    const int lp = t >> 6;
    const int pt = blockIdx.x * 4 + lp;
    const int b = pt >> 8;
    const size_t base = (size_t)pt * 20;
    float sum = 0.f, mx = -3.402823466e38f;
    for (int k = 0; k < 20; ++k) {
        int q = idx[base + k];
        float wv = wgt[base + k];
        float val = __bfloat162float(h[(((size_t)b << 8) + q) * 64 + f]) * wv;
        sum += val;
        mx = fmaxf(mx, val);
    }
    bf16* out = xtgt + (size_t)pt * stride + fiL;
    out[f] = __float2bfloat16(sum * (1.f / 20.f));
    out[64 + f] = __float2bfloat16(mx);
    if (f < padN) out[128 + f] = __float2bfloat16(0.f);
}

// ---------------------------------------------------------------------------
__global__ __launch_bounds__(256) void init_mid(float* __restrict__ mid,
                                                const float* __restrict__ b_mid)
{
    size_t i = (size_t)blockIdx.x * 256 + threadIdx.x;
    mid[i] = b_mid[i & 511];
}

// ---------------------------------------------------------------------------
// Multi-pool (min,max,mean,sum,std,median-lower); median via bitonic sort.
// ---------------------------------------------------------------------------
__global__ __launch_bounds__(256) void pool_kernel(
    const float* __restrict__ mid,   // [B*P, 512]
    float* __restrict__ pooled)      // [B, 3072]
{
    __shared__ float tile[GP][33];
    __shared__ float rbuf[256];
    const int b = blockIdx.x;
    const int c0 = blockIdx.y * 32;
    const int t = threadIdx.x;

    #pragma unroll 8
    for (int l = 0; l < 32; ++l) {
        int lin = l * 256 + t;
        int row = lin >> 5;
        int col = lin & 31;
        tile[row][col] = mid[((size_t)b * GP + row) * 512 + c0 + col];
    }
    __syncthreads();

    const int col = t & 31, g = t >> 5;
    float mn = 3.402823466e38f, mx = -3.402823466e38f, sm = 0.f, s2 = 0.f;
    for (int r = g * 32; r < g * 32 + 32; ++r) {
        float v = tile[r][col];
        mn = fminf(mn, v); mx = fmaxf(mx, v); sm += v; s2 += v * v;
    }
    float* outb = pooled + (size_t)b * 3072 + c0;

    rbuf[t] = mn; __syncthreads();
    if (t < 32) {
        float v = rbuf[t];
        #pragma unroll
        for (int k = 1; k < 8; ++k) v = fminf(v, rbuf[t + 32 * k]);
        outb[0 * 512 + t] = v;
    }
    __syncthreads();
    rbuf[t] = mx; __syncthreads();
    if (t < 32) {
        float v = rbuf[t];
        #pragma unroll
        for (int k = 1; k < 8; ++k) v = fmaxf(v, rbuf[t + 32 * k]);
        outb[1 * 512 + t] = v;
    }
    __syncthreads();
    rbuf[t] = sm; __syncthreads();
    float meanv = 0.f;
    if (t < 32) {
        float v = 0.f;
        #pragma unroll
        for (int k = 0; k < 8; ++k) v += rbuf[t + 32 * k];
        meanv = v * (1.f / 256.f);
        outb[2 * 512 + t] = meanv;
        outb[3 * 512 + t] = v;
    }
    __syncthreads();
    rbuf[t] = s2; __syncthreads();
    if (t < 32) {
        float v = 0.f;
        #pragma unroll
        for (int k = 0; k < 8; ++k) v += rbuf[t + 32 * k];
        float var = v * (1.f / 256.f) - meanv * meanv;
        outb[4 * 512 + t] = sqrtf(fmaxf(var, 0.f) + 1e-5f);
    }

    for (int size = 2; size <= 256; size <<= 1) {
        for (int stride = size >> 1; stride > 0; stride >>= 1) {
            __syncthreads();
            #pragma unroll
            for (int it = 0; it < 16; ++it) {
                int task = it * 256 + t;
                int c = task & 31;
                int pp = task >> 5;
                int i = 2 * pp - (pp & (stride - 1));
                int j = i + stride;
                bool up = ((i & size) == 0);
                float va = tile[i][c], vb = tile[j][c];
                bool sw = up ? (va > vb) : (va < vb);
                if (sw) { tile[i][c] = vb; tile[j][c] = va; }
            }
        }
    }
    __syncthreads();
    if (t < 32) outb[5 * 512 + t] = tile[127][t];
}

// ---------------------------------------------------------------------------
__global__ __launch_bounds__(128) void head_kernel(
    const float* __restrict__ pooled,  // [B, 3072]
    const float* __restrict__ Wh,      // [3072, 128]
    const float* __restrict__ bh,      // [128]
    float* __restrict__ out)           // [B, 128]
{
    __shared__ float sh[3072];
    const int b = blockIdx.x, t = threadIdx.x;
    for (int l = t; l < 3072; l += 128) sh[l] = pooled[(size_t)b * 3072 + l];
    __syncthreads();
    float acc = bh[t];
    for (int k = 0; k < 3072; ++k) acc += sh[k] * Wh[(size_t)k * 128 + t];
    out[(size_t)b * 128 + t] = acc;
}

// ---------------------------------------------------------------------------
extern "C" void kernel_launch(void* const* d_in, const int* in_sizes, int n_in,
                              void* d_out, int out_size, void* d_ws, size_t ws_size,
                              hipStream_t stream)
{
    const int fi[8] = {8, 256, 256, 512, 512, 512, 1024, 1024};
    const int fo[8] = {256, 256, 512, 512, 512, 1024, 1024, 1024};
    const int Kh[8] = {64, 256, 256, 512, 512, 512, 1024, 1024};
    const int Ko[8] = {192, 384, 384, 640, 640, 640, 1152, 1152};
    const int Km[9] = {64, 256, 256, 512, 512, 512, 1024, 1024, 1024};
    const int S[9]  = {192, 384, 384, 640, 640, 640, 1152, 1152, 1024};

    const float* x      = (const float*)d_in[0];
    const float* W_mid  = (const float*)d_in[50];
    const float* b_mid  = (const float*)d_in[51];
    const float* W_head = (const float*)d_in[52];
    const float* b_head = (const float*)d_in[53];

    const size_t M = M_ROWS;

    char* p = (char*)d_ws;
    float* mid    = (float*)p; p += M * 512 * 4;
    float* sbuf   = (float*)p; p += M * 8 * 4;
    float* pooled = (float*)p; p += 128 * 3072 * 4;
    float* wgtb   = (float*)p; p += M * 20 * 4;
    int*   idxb   = (int*)p;   p += M * 20 * 4;
    bf16*  hbuf   = (bf16*)p;  p += M * 64 * 2;
    bf16*  xA     = (bf16*)p;  p += M * 1152 * 2;
    bf16*  xB     = (bf16*)p;  p += M * 1152 * 2;
    float* biassh = (float*)p; p += 8 * 128 * 4;
    bf16*  wpool  = (bf16*)p;
    bf16* wsh[8]; bf16* wto[8]; bf16* wtm[9];
    {
        bf16* wp = wpool;
        for (int L = 0; L < 8; ++L) { wsh[L] = wp; wp += (size_t)128 * Kh[L]; }
        for (int L = 0; L < 8; ++L) { wto[L] = wp; wp += (size_t)fo[L] * Ko[L]; }
        for (int i = 0; i < 9; ++i) { wtm[i] = wp; wp += (size_t)512 * Km[i]; }
        p = (char*)wp;
    }
    size_t needed = (size_t)(p - (char*)d_ws);
    if (ws_size < needed) {
        diag_kernel<<<1, 1, 0, stream>>>((float*)d_out, (float)ws_size);
        return;
    }

    BiasArgs ba;
    for (int L = 0; L < 8; ++L) {
        const float* Ws = (const float*)d_in[2 + 6 * L];
        const float* bs = (const float*)d_in[3 + 6 * L];
        const float* Wh = (const float*)d_in[4 + 6 * L];
        const float* bh = (const float*)d_in[5 + 6 * L];
        const float* Wo = (const float*)d_in[6 + 6 * L];
        ba.bh[L] = bh; ba.bs[L] = bs;
        wprep_sh<<<dim3((Kh[L] + 255) / 256, 128), 256, 0, stream>>>(
            Wh, Ws, wsh[L], fi[L], Kh[L]);
        wprep_t<<<dim3(Ko[L] / 32, fo[L] / 32), dim3(32, 8), 0, stream>>>(
            Wo, wto[L], fi[L] + 128, fo[L], Ko[L]);
    }
    bias_build_all<<<8, 128, 0, stream>>>(ba, biassh);
    wprep_mid_all<<<dim3(162, 16), dim3(32, 8), 0, stream>>>(W_mid, wtm[0]);

    f2b_pad<<<(int)(M * 8 / 256), 256, 0, stream>>>(x, xA);
    init_mid<<<(int)(M * 512 / 256), 256, 0, stream>>>(mid, b_mid);

    bf16* bufs[2] = {xA, xB};
    for (int L = 0; L < 8; ++L) {
        bf16* xin = bufs[L & 1];
        bf16* xout = bufs[(L + 1) & 1];
        const float* bo = (const float*)d_in[7 + 6 * L];

        mgemm<0><<<dim3(256, 1), 256, 0, stream>>>(
            xin, S[L], wsh[L], biassh + L * 128, (float*)hbuf, 64, sbuf, Kh[L]);
        knn_kernel<<<(int)(M / 4), 256, 0, stream>>>(sbuf, idxb, wgtb);
        gather_kernel<<<(int)(M / 4), 256, 0, stream>>>(
            hbuf, idxb, wgtb, xin, S[L], fi[L], (L == 0) ? 56 : 0);
        mgemm<2><<<dim3(256, 4), 256, 0, stream>>>(
            xin, S[L], wtm[L], nullptr, mid, 512, nullptr, Km[L]);
        mgemm<1><<<dim3(256, fo[L] / 128), 256, 0, stream>>>(
            xin, S[L], wto[L], bo, (float*)xout, S[L + 1], nullptr, Ko[L]);
    }
    mgemm<2><<<dim3(256, 4), 256, 0, stream>>>(
        bufs[0], S[8], wtm[8], nullptr, mid, 512, nullptr, Km[8]);

    pool_kernel<<<dim3(GB, 16), 256, 0, stream>>>(mid, pooled);
    head_kernel<<<GB, 128, 0, stream>>>(pooled, W_head, b_head, (float*)d_out);
}

// Round 9
// 2080.647 us; speedup vs baseline: 6.9909x; 1.0438x over previous
//
#include <hip/hip_runtime.h>
#include <hip/hip_bf16.h>
#include <math.h>

#define M_ROWS 32768   // B*P
#define GB 128         // graphs
#define GP 256         // points per graph

typedef __hip_bfloat16 bf16;
typedef __attribute__((ext_vector_type(8))) short short8;
typedef __attribute__((ext_vector_type(4))) float f32x4;

// ---------------------------------------------------------------------------
__global__ void diag_kernel(float* out, float v) { out[0] = v; }

// ---------------------------------------------------------------------------
// MFMA GEMM, m97 structure: global_load_lds(16B) staging, linear LDS, 2-barrier
// K-loop. BM=128, BN=128, BK=64, 256 threads = 4 waves (2x2), 16x16x32 bf16.
// A is split-region: K-tiles < splitTile read from A1 (lda1), else A2 (lda2).
// MODE 0: cols<64 -> hbuf bf16 [M,64]; cols 64..71 -> sbuf f32 [M,8]
// MODE 1: out bf16 [M,ldc], bias+relu
// MODE 2: out f32 [M,ldc] += (accumulate, no bias)
// MODE 3: out f32 [M,ldc] = v + bias (one-shot mid)
// ---------------------------------------------------------------------------
template<int MODE>
__global__ __launch_bounds__(256) void mgemm(
    const bf16* __restrict__ A1, int lda1,
    const bf16* __restrict__ A2, int lda2, int splitTile,
    const bf16* __restrict__ Wt,              // [N, K] bf16 (W^T) row-major
    const float* __restrict__ bias,           // [N] f32 (unused MODE2)
    float* __restrict__ out0, int ldc,
    float* __restrict__ out1,                 // MODE0: sbuf
    int K)
{
    __shared__ unsigned short Alds[128][64];
    __shared__ unsigned short Blds[128][64];
    const int tid = threadIdx.x;
    const int l = tid & 63;
    const int w = tid >> 6;
    const int wr = w >> 1, wc = w & 1;
    const int rowBase = blockIdx.x * 128;
    const int colBase = blockIdx.y * 128;

    const int lr = l >> 3;          // 0..7
    const int lc = (l & 7) * 8;     // 0..56
    const int arow = rowBase + w * 32 + lr;
    const bf16* A1b = A1 + (size_t)arow * lda1 + lc;
    const bf16* A2b = A2 ? (A2 + (size_t)arow * lda2 + lc) : A1b;
    const bf16* Bb  = Wt + (size_t)(colBase + w * 32 + lr) * K + lc;

    f32x4 acc[4][4];
    #pragma unroll
    for (int m = 0; m < 4; ++m)
        #pragma unroll
        for (int n = 0; n < 4; ++n)
            acc[m][n] = (f32x4){0.f, 0.f, 0.f, 0.f};

    const int nt = K >> 6;
    for (int t = 0; t < nt; ++t) {
        const bf16* bp; int ldsel; int ko;
        if (t < splitTile) { bp = A1b; ldsel = lda1; ko = t << 6; }
        else               { bp = A2b; ldsel = lda2; ko = (t - splitTile) << 6; }
        const int kb = t << 6;
        __syncthreads();
        #pragma unroll
        for (int j = 0; j < 4; ++j) {
            __builtin_amdgcn_global_load_lds(
                (const __attribute__((address_space(1))) void*)(bp + (size_t)(j * 8) * ldsel + ko),
                (__attribute__((address_space(3))) void*)&Alds[w * 32 + j * 8][0],
                16, 0, 0);
            __builtin_amdgcn_global_load_lds(
                (const __attribute__((address_space(1))) void*)(Bb + (size_t)(j * 8) * K + kb),
                (__attribute__((address_space(3))) void*)&Blds[w * 32 + j * 8][0],
                16, 0, 0);
        }
        __syncthreads();
        #pragma unroll
        for (int kk = 0; kk < 2; ++kk) {
            const int co = kk * 32 + (l >> 4) * 8;
            short8 a[4], b[4];
            #pragma unroll
            for (int m = 0; m < 4; ++m)
                a[m] = *(const short8*)&Alds[wr * 64 + m * 16 + (l & 15)][co];
            #pragma unroll
            for (int n = 0; n < 4; ++n)
                b[n] = *(const short8*)&Blds[wc * 64 + n * 16 + (l & 15)][co];
            #pragma unroll
            for (int m = 0; m < 4; ++m)
                #pragma unroll
                for (int n = 0; n < 4; ++n)
                    acc[m][n] = __builtin_amdgcn_mfma_f32_16x16x32_bf16(
                        a[m], b[n], acc[m][n], 0, 0, 0);
        }
    }

    // epilogue: C/D layout col=lane&15, row=(lane>>4)*4+reg  [m89/m91]
    const int r0 = rowBase + wr * 64 + (l >> 4) * 4;
    const int c0 = colBase + wc * 64 + (l & 15);
    #pragma unroll
    for (int m = 0; m < 4; ++m) {
        #pragma unroll
        for (int n = 0; n < 4; ++n) {
            const int col = c0 + n * 16;
            const float bv = (MODE == 2) ? 0.f : bias[col];
            #pragma unroll
            for (int g = 0; g < 4; ++g) {
                const int row = r0 + m * 16 + g;
                float v = acc[m][n][g] + bv;
                if (MODE == 0) {
                    if (col < 64)
                        ((bf16*)out0)[(size_t)row * 64 + col] = __float2bfloat16(v);
                    else if (col < 72)
                        out1[(size_t)row * 8 + (col - 64)] = v;
                } else if (MODE == 1) {
                    ((bf16*)out0)[(size_t)row * ldc + col] =
                        __float2bfloat16(fmaxf(v, 0.f));
                } else if (MODE == 2) {
                    out0[(size_t)row * ldc + col] += v;
                } else {
                    out0[(size_t)row * ldc + col] = v;
                }
            }
        }
    }
}

// ---------------------------------------------------------------------------
// Wo prep: Wt[n, k] (bf16, [N,Kpad]) from W [fiReal+128, N] f32 with a gap:
// k<fiReal -> row k; fiPad<=k<fiPad+128 -> row k-fiPad+fiReal; else 0.
// ---------------------------------------------------------------------------
__global__ __launch_bounds__(256) void wprep_t(
    const float* __restrict__ W, bf16* __restrict__ Wt,
    int fiReal, int fiPad, int N, int Kpad)
{
    __shared__ float tl[32][33];
    const int tx = threadIdx.x, ty = threadIdx.y;
    const int k_t = blockIdx.x * 32, n_t = blockIdx.y * 32;
    #pragma unroll
    for (int j = 0; j < 4; ++j) {
        int k = k_t + ty + j * 8;
        int s = (k < fiReal) ? k : ((k >= fiPad) ? (k - fiPad + fiReal) : -1);
        float v = 0.f;
        if (s >= 0 && s < fiReal + 128) v = W[(size_t)s * N + n_t + tx];
        tl[ty + j * 8][tx] = v;
    }
    __syncthreads();
    #pragma unroll
    for (int j = 0; j < 4; ++j) {
        int n = n_t + ty + j * 8;
        Wt[(size_t)n * Kpad + k_t + tx] = __float2bfloat16(tl[tx][ty + j * 8]);
    }
}

// ---------------------------------------------------------------------------
// Segmented W_mid prep (small path). grid (162,16).
// ---------------------------------------------------------------------------
__global__ __launch_bounds__(256) void wprep_mid_all(
    const float* __restrict__ W_mid, bf16* __restrict__ wtm0)
{
    const int segBlkStart[10] = {0, 2, 10, 18, 34, 50, 66, 98, 130, 162};
    const int segKm[9]   = {64, 256, 256, 512, 512, 512, 1024, 1024, 1024};
    const int segKr[9]   = {8, 256, 256, 512, 512, 512, 1024, 1024, 1024};
    const int segMrow[9] = {0, 8, 264, 520, 1032, 1544, 2056, 3080, 4104};
    const int segWOff[9] = {0, 32768, 163840, 294912, 557056, 819200,
                            1081344, 1605632, 2129920};
    __shared__ float tl[32][33];
    int bx = blockIdx.x;
    int seg = 0;
    while (bx >= segBlkStart[seg + 1]) ++seg;
    const int kb = bx - segBlkStart[seg];
    const float* W = W_mid + (size_t)segMrow[seg] * 512;
    bf16* Wt = wtm0 + segWOff[seg];
    const int K = segKr[seg], Kpad = segKm[seg];
    const int tx = threadIdx.x, ty = threadIdx.y;
    const int k_t = kb * 32, n_t = blockIdx.y * 32;
    #pragma unroll
    for (int j = 0; j < 4; ++j) {
        int k = k_t + ty + j * 8;
        tl[ty + j * 8][tx] = (k < K) ? W[(size_t)k * 512 + n_t + tx] : 0.f;
    }
    __syncthreads();
    #pragma unroll
    for (int j = 0; j < 4; ++j) {
        int n = n_t + ty + j * 8;
        Wt[(size_t)n * Kpad + k_t + tx] = __float2bfloat16(tl[tx][ty + j * 8]);
    }
}

// ---------------------------------------------------------------------------
// One-shot W_mid prep (big path): Wt [512, 5184] bf16 from W_mid [5128,512].
// K-offsets per segment are 64-aligned (x0 padded 8->64). grid (162,16).
// ---------------------------------------------------------------------------
__global__ __launch_bounds__(256) void wprep_mid_big(
    const float* __restrict__ W_mid, bf16* __restrict__ Wt)
{
    const int off_[9]  = {0, 64, 320, 576, 1088, 1600, 2112, 3136, 4160};
    const int size_[9] = {8, 256, 256, 512, 512, 512, 1024, 1024, 1024};
    const int mrow_[9] = {0, 8, 264, 520, 1032, 1544, 2056, 3080, 4104};
    __shared__ float tl[32][33];
    const int tx = threadIdx.x, ty = threadIdx.y;
    const int k_t = blockIdx.x * 32, n_t = blockIdx.y * 32;
    #pragma unroll
    for (int j = 0; j < 4; ++j) {
        int k = k_t + ty + j * 8;
        int s = -1;
        #pragma unroll
        for (int g = 0; g < 9; ++g)
            if (k >= off_[g] && k < off_[g] + size_[g]) s = mrow_[g] + (k - off_[g]);
        tl[ty + j * 8][tx] = (s >= 0) ? W_mid[(size_t)s * 512 + n_t + tx] : 0.f;
    }
    __syncthreads();
    #pragma unroll
    for (int j = 0; j < 4; ++j) {
        int n = n_t + ty + j * 8;
        Wt[(size_t)n * 5184 + k_t + tx] = __float2bfloat16(tl[tx][ty + j * 8]);
    }
}

// ---------------------------------------------------------------------------
// W_sh^T [128, Khpad]: rows 0..63 = Wh^T; 64..67 = hi(Ws^T); 68..71 = lo(Ws^T)
// ---------------------------------------------------------------------------
__global__ __launch_bounds__(256) void wprep_sh(
    const float* __restrict__ Wh, const float* __restrict__ Ws,
    bf16* __restrict__ Wt, int fi, int Khpad)
{
    const int k = blockIdx.x * 256 + threadIdx.x;
    const int n = blockIdx.y;
    if (k >= Khpad) return;
    float v = 0.f;
    if (k < fi) {
        if (n < 64) v = Wh[(size_t)k * 64 + n];
        else if (n < 68) {
            v = __bfloat162float(__float2bfloat16(Ws[(size_t)k * 4 + (n - 64)]));
        } else if (n < 72) {
            float wv = Ws[(size_t)k * 4 + (n - 68)];
            float hi = __bfloat162float(__float2bfloat16(wv));
            v = wv - hi;
        }
    }
    Wt[(size_t)n * Khpad + k] = __float2bfloat16(v);
}

struct BiasArgs { const float* bh[8]; const float* bs[8]; };
__global__ __launch_bounds__(128) void bias_build_all(
    BiasArgs a, float* __restrict__ out)
{
    const int L = blockIdx.x, t = threadIdx.x;
    out[L * 128 + t] = (t < 64) ? a.bh[L][t] : (t < 68 ? a.bs[L][t - 64] : 0.f);
}

// ---------------------------------------------------------------------------
__global__ __launch_bounds__(256) void f2b_pad(const float* __restrict__ in,
                                               bf16* __restrict__ out)
{
    int i = blockIdx.x * 256 + threadIdx.x;
    int row = i >> 3, c = i & 7;
    out[(size_t)row * 192 + c] = __float2bfloat16(in[i]);
}

__global__ __launch_bounds__(256) void f2b_big(const float* __restrict__ in,
                                               bf16* __restrict__ feat)
{
    int i = blockIdx.x * 256 + threadIdx.x;   // M*64
    int row = i >> 6, c = i & 63;
    feat[(size_t)row * 5184 + c] =
        __float2bfloat16(c < 8 ? in[row * 8 + c] : 0.f);
}

// ---------------------------------------------------------------------------
// Wave-64 integer min reduce via DPP (VALU pipe), result broadcast via
// readlane(63). Valid for non-negative-float bit patterns.
// ---------------------------------------------------------------------------
__device__ __forceinline__ int wave_imin_bcast(int x)
{
    int y;
    y = __builtin_amdgcn_update_dpp(x, x, 0x111, 0xf, 0xf, false); x = y < x ? y : x;
    y = __builtin_amdgcn_update_dpp(x, x, 0x112, 0xf, 0xf, false); x = y < x ? y : x;
    y = __builtin_amdgcn_update_dpp(x, x, 0x114, 0xf, 0xf, false); x = y < x ? y : x;
    y = __builtin_amdgcn_update_dpp(x, x, 0x118, 0xf, 0xf, false); x = y < x ? y : x;
    y = __builtin_amdgcn_update_dpp(x, x, 0x142, 0xf, 0xf, false); x = y < x ? y : x;
    y = __builtin_amdgcn_update_dpp(x, x, 0x143, 0xf, 0xf, false); x = y < x ? y : x;
    return __builtin_amdgcn_readlane(x, 63);
}

// ---------------------------------------------------------------------------
// kNN, wave-per-point: 4 waves/block, grid M/4. Lane holds 4 sorted (d,q)
// pairs in named regs; 20 rounds of {DPP-min, ballot-winner, branchless pop};
// results gathered in lanes 0..19 -> coalesced stores. d clamped >= 0 so
// int-compare == float-compare.
// ---------------------------------------------------------------------------
__global__ __launch_bounds__(256) void knn_kernel(
    const float* __restrict__ sbuf,   // [B*P, 8] (hi/lo split)
    int* __restrict__ idx,            // [B*P, 20]
    float* __restrict__ wgt)          // [B*P, 20]
{
    __shared__ float ss[GP][5];
    const int t = threadIdx.x;
    const int b = blockIdx.x >> 6;
    {
        const float4 v1 = ((const float4*)(sbuf + ((size_t)b * GP + t) * 8))[0];
        const float4 v2 = ((const float4*)(sbuf + ((size_t)b * GP + t) * 8))[1];
        float ax = v1.x + v2.x, ay = v1.y + v2.y,
              az = v1.z + v2.z, aw = v1.w + v2.w;
        ss[t][0] = ax; ss[t][1] = ay; ss[t][2] = az; ss[t][3] = aw;
        ss[t][4] = ax * ax + ay * ay + az * az + aw * aw;
    }
    __syncthreads();

    const int w = t >> 6, l = t & 63;
    const int p = (blockIdx.x * 4 + w) & 255;
    const float px = ss[p][0], py = ss[p][1], pz = ss[p][2], pq = ss[p][3];
    const float psq = ss[p][4];

    float d0, d1, d2, d3; int q0, q1, q2, q3;
    #define KNN_DIST(DD, QQ, J) { \
        const int q_ = l + (J) * 64; \
        float dot_ = px * ss[q_][0] + py * ss[q_][1] \
                   + pz * ss[q_][2] + pq * ss[q_][3]; \
        DD = fmaxf(psq + ss[q_][4] - 2.f * dot_, 0.f); QQ = q_; }
    KNN_DIST(d0, q0, 0) KNN_DIST(d1, q1, 1)
    KNN_DIST(d2, q2, 2) KNN_DIST(d3, q3, 3)
    #undef KNN_DIST
    #define KNN_CE(DA, DB, QA, QB) { \
        if (DA > DB) { float td = DA; DA = DB; DB = td; \
                       int tq = QA; QA = QB; QB = tq; } }
    KNN_CE(d0, d1, q0, q1) KNN_CE(d2, d3, q2, q3)
    KNN_CE(d0, d2, q0, q2) KNN_CE(d1, d3, q1, q3)
    KNN_CE(d1, d2, q1, q2)
    #undef KNN_CE

    float outd = 0.f; int outq = 0;
    #pragma unroll
    for (int k = 0; k < 20; ++k) {
        const int mb = wave_imin_bcast(__float_as_int(d0));
        unsigned long long msk = __ballot(__float_as_int(d0) == mb);
        const int winner = __ffsll((long long)msk) - 1;
        const int qwin = __builtin_amdgcn_readlane(q0, winner);
        if (l == k) { outd = __int_as_float(mb); outq = qwin; }
        const bool pop = (l == winner);
        d0 = pop ? d1 : d0; q0 = pop ? q1 : q0;
        d1 = pop ? d2 : d1; q1 = pop ? q2 : q1;
        d2 = pop ? d3 : d2; q2 = pop ? q3 : q2;
        d3 = pop ? 3.402823466e38f : d3;
    }
    if (l < 20) {
        const size_t base = ((size_t)b * GP + p) * 20;
        idx[base + l] = outq;
        wgt[base + l] = expf(-10.f * outd);
    }
}

// ---------------------------------------------------------------------------
__global__ __launch_bounds__(256) void gather_kernel(
    const bf16* __restrict__ h, const int* __restrict__ idx,
    const float* __restrict__ wgt,
    bf16* __restrict__ xtgt, int stride, int fiL, int padN)
{
    const int t = threadIdx.x;
    const int f = t & 63;
    const int lp = t >> 6;
    const int pt = blockIdx.x * 4 + lp;
    const int b = pt >> 8;
    const size_t base = (size_t)pt * 20;
    float sum = 0.f, mx = -3.402823466e38f;
    for (int k = 0; k < 20; ++k) {
        int q = idx[base + k];
        float wv = wgt[base + k];
        float val = __bfloat162float(h[(((size_t)b << 8) + q) * 64 + f]) * wv;
        sum += val;
        mx = fmaxf(mx, val);
    }
    bf16* out = xtgt + (size_t)pt * stride + fiL;
    out[f] = __float2bfloat16(sum * (1.f / 20.f));
    out[64 + f] = __float2bfloat16(mx);
    if (f < padN) out[128 + f] = __float2bfloat16(0.f);
}

// ---------------------------------------------------------------------------
__global__ __launch_bounds__(256) void init_mid(float* __restrict__ mid,
                                                const float* __restrict__ b_mid)
{
    size_t i = (size_t)blockIdx.x * 256 + threadIdx.x;
    mid[i] = b_mid[i & 511];
}

// ---------------------------------------------------------------------------
// Multi-pool (min,max,mean,sum,std,median-lower); median via bitonic sort.
// ---------------------------------------------------------------------------
__global__ __launch_bounds__(256) void pool_kernel(
    const float* __restrict__ mid, float* __restrict__ pooled)
{
    __shared__ float tile[GP][33];
    __shared__ float rbuf[256];
    const int b = blockIdx.x;
    const int c0 = blockIdx.y * 32;
    const int t = threadIdx.x;

    #pragma unroll 8
    for (int l = 0; l < 32; ++l) {
        int lin = l * 256 + t;
        int row = lin >> 5;
        int col = lin & 31;
        tile[row][col] = mid[((size_t)b * GP + row) * 512 + c0 + col];
    }
    __syncthreads();

    const int col = t & 31, g = t >> 5;
    float mn = 3.402823466e38f, mx = -3.402823466e38f, sm = 0.f, s2 = 0.f;
    for (int r = g * 32; r < g * 32 + 32; ++r) {
        float v = tile[r][col];
        mn = fminf(mn, v); mx = fmaxf(mx, v); sm += v; s2 += v * v;
    }
    float* outb = pooled + (size_t)b * 3072 + c0;

    rbuf[t] = mn; __syncthreads();
    if (t < 32) {
        float v = rbuf[t];
        #pragma unroll
        for (int k = 1; k < 8; ++k) v = fminf(v, rbuf[t + 32 * k]);
        outb[0 * 512 + t] = v;
    }
    __syncthreads();
    rbuf[t] = mx; __syncthreads();
    if (t < 32) {
        float v = rbuf[t];
        #pragma unroll
        for (int k = 1; k < 8; ++k) v = fmaxf(v, rbuf[t + 32 * k]);
        outb[1 * 512 + t] = v;
    }
    __syncthreads();
    rbuf[t] = sm; __syncthreads();
    float meanv = 0.f;
    if (t < 32) {
        float v = 0.f;
        #pragma unroll
        for (int k = 0; k < 8; ++k) v += rbuf[t + 32 * k];
        meanv = v * (1.f / 256.f);
        outb[2 * 512 + t] = meanv;
        outb[3 * 512 + t] = v;
    }
    __syncthreads();
    rbuf[t] = s2; __syncthreads();
    if (t < 32) {
        float v = 0.f;
        #pragma unroll
        for (int k = 0; k < 8; ++k) v += rbuf[t + 32 * k];
        float var = v * (1.f / 256.f) - meanv * meanv;
        outb[4 * 512 + t] = sqrtf(fmaxf(var, 0.f) + 1e-5f);
    }

    for (int size = 2; size <= 256; size <<= 1) {
        for (int stride = size >> 1; stride > 0; stride >>= 1) {
            __syncthreads();
            #pragma unroll
            for (int it = 0; it < 16; ++it) {
                int task = it * 256 + t;
                int c = task & 31;
                int pp = task >> 5;
                int i = 2 * pp - (pp & (stride - 1));
                int j = i + stride;
                bool up = ((i & size) == 0);
                float va = tile[i][c], vb = tile[j][c];
                bool sw = up ? (va > vb) : (va < vb);
                if (sw) { tile[i][c] = vb; tile[j][c] = va; }
            }
        }
    }
    __syncthreads();
    if (t < 32) outb[5 * 512 + t] = tile[127][t];
}

// ---------------------------------------------------------------------------
__global__ __launch_bounds__(128) void head_kernel(
    const float* __restrict__ pooled, const float* __restrict__ Wh,
    const float* __restrict__ bh, float* __restrict__ out)
{
    __shared__ float sh[3072];
    const int b = blockIdx.x, t = threadIdx.x;
    for (int l = t; l < 3072; l += 128) sh[l] = pooled[(size_t)b * 3072 + l];
    __syncthreads();
    float acc = bh[t];
    for (int k = 0; k < 3072; ++k) acc += sh[k] * Wh[(size_t)k * 128 + t];
    out[(size_t)b * 128 + t] = acc;
}

// ---------------------------------------------------------------------------
extern "C" void kernel_launch(void* const* d_in, const int* in_sizes, int n_in,
                              void* d_out, int out_size, void* d_ws, size_t ws_size,
                              hipStream_t stream)
{
    const int fi[8]  = {8, 256, 256, 512, 512, 512, 1024, 1024};
    const int fip[8] = {64, 256, 256, 512, 512, 512, 1024, 1024};  // 64-padded
    const int fo[8]  = {256, 256, 512, 512, 512, 1024, 1024, 1024};
    const int Kh[8]  = {64, 256, 256, 512, 512, 512, 1024, 1024};
    const int Ko[8]  = {192, 384, 384, 640, 640, 640, 1152, 1152};
    const int Km[9]  = {64, 256, 256, 512, 512, 512, 1024, 1024, 1024};
    const int off[9] = {0, 64, 320, 576, 1088, 1600, 2112, 3136, 4160}; // feat cols
    const int S[9]   = {192, 384, 384, 640, 640, 640, 1152, 1152, 1024}; // small-path strides

    const float* x      = (const float*)d_in[0];
    const float* W_mid  = (const float*)d_in[50];
    const float* b_mid  = (const float*)d_in[51];
    const float* W_head = (const float*)d_in[52];
    const float* b_head = (const float*)d_in[53];

    const size_t M = M_ROWS;

    // -------- common small buffers (identical in both layouts head) --------
    char* p = (char*)d_ws;
    float* mid    = (float*)p; p += M * 512 * 4;
    float* sbuf   = (float*)p; p += M * 8 * 4;
    float* pooled = (float*)p; p += 128 * 3072 * 4;
    float* wgtb   = (float*)p; p += M * 20 * 4;
    int*   idxb   = (int*)p;   p += M * 20 * 4;
    float* biassh = (float*)p; p += 8 * 128 * 4;
    bf16*  hbuf   = (bf16*)p;  p += M * 64 * 2;

    // -------- big-path layout --------
    char* pb = p;
    bf16* aggb = (bf16*)pb; pb += M * 128 * 2;
    bf16* feat = (bf16*)pb; pb += M * 5184 * 2;
    bf16* wshB = (bf16*)pb;
    {
        bf16* wp = wshB;
        for (int L = 0; L < 8; ++L) wp += (size_t)128 * Kh[L];
        pb = (char*)wp;
    }
    bf16* wtoB = (bf16*)pb;
    {
        bf16* wp = wtoB;
        for (int L = 0; L < 8; ++L) wp += (size_t)fo[L] * Ko[L];
        pb = (char*)wp;
    }
    bf16* wtmB = (bf16*)pb; pb += (size_t)512 * 5184 * 2;
    const size_t neededBig = (size_t)(pb - (char*)d_ws);

    // -------- small-path layout --------
    char* ps = p;
    bf16* xA = (bf16*)ps; ps += M * 1152 * 2;
    bf16* xB = (bf16*)ps; ps += M * 1152 * 2;
    bf16* wshS = (bf16*)ps;
    {
        bf16* wp = wshS;
        for (int L = 0; L < 8; ++L) wp += (size_t)128 * Kh[L];
        ps = (char*)wp;
    }
    bf16* wtoS = (bf16*)ps;
    {
        bf16* wp = wtoS;
        for (int L = 0; L < 8; ++L) wp += (size_t)fo[L] * Ko[L];
        ps = (char*)wp;
    }
    bf16* wtmS = (bf16*)ps;
    {
        bf16* wp = wtmS;
        for (int i = 0; i < 9; ++i) wp += (size_t)512 * Km[i];
        ps = (char*)wp;
    }
    const size_t neededSmall = (size_t)(ps - (char*)d_ws);

    if (ws_size < neededSmall) {
        diag_kernel<<<1, 1, 0, stream>>>((float*)d_out, (float)ws_size);
        return;
    }
    const bool big = (ws_size >= neededBig);

    // -------- weight prep --------
    BiasArgs ba;
    bf16* wsh[8]; bf16* wto[8];
    {
        bf16* wp = big ? wshB : wshS;
        for (int L = 0; L < 8; ++L) { wsh[L] = wp; wp += (size_t)128 * Kh[L]; }
        wp = big ? wtoB : wtoS;
        for (int L = 0; L < 8; ++L) { wto[L] = wp; wp += (size_t)fo[L] * Ko[L]; }
    }
    for (int L = 0; L < 8; ++L) {
        const float* Ws = (const float*)d_in[2 + 6 * L];
        const float* bs = (const float*)d_in[3 + 6 * L];
        const float* Wh = (const float*)d_in[4 + 6 * L];
        const float* bh = (const float*)d_in[5 + 6 * L];
        const float* Wo = (const float*)d_in[6 + 6 * L];
        ba.bh[L] = bh; ba.bs[L] = bs;
        wprep_sh<<<dim3((Kh[L] + 255) / 256, 128), 256, 0, stream>>>(
            Wh, Ws, wsh[L], fi[L], Kh[L]);
        wprep_t<<<dim3(Ko[L] / 32, fo[L] / 32), dim3(32, 8), 0, stream>>>(
            Wo, wto[L], fi[L], big ? fip[L] : fi[L], fo[L], Ko[L]);
    }
    bias_build_all<<<8, 128, 0, stream>>>(ba, biassh);

    if (big) {
        wprep_mid_big<<<dim3(162, 16), dim3(32, 8), 0, stream>>>(W_mid, wtmB);
        f2b_big<<<(int)(M * 64 / 256), 256, 0, stream>>>(x, feat);

        for (int L = 0; L < 8; ++L) {
            const float* bo = (const float*)d_in[7 + 6 * L];
            mgemm<0><<<dim3(256, 1), 256, 0, stream>>>(
                feat + off[L], 5184, nullptr, 0, 9999,
                wsh[L], biassh + L * 128, (float*)hbuf, 64, sbuf, Kh[L]);
            knn_kernel<<<(int)(M / 4), 256, 0, stream>>>(sbuf, idxb, wgtb);
            gather_kernel<<<(int)(M / 4), 256, 0, stream>>>(
                hbuf, idxb, wgtb, aggb, 128, 0, 0);
            mgemm<1><<<dim3(256, fo[L] / 128), 256, 0, stream>>>(
                feat + off[L], 5184, aggb, 128, fip[L] >> 6,
                wto[L], bo, (float*)(feat + off[L + 1]), 5184, nullptr, Ko[L]);
        }
        // one-shot mid = feat @ Wmid^T + b_mid
        mgemm<3><<<dim3(256, 4), 256, 0, stream>>>(
            feat, 5184, nullptr, 0, 9999,
            wtmB, b_mid, mid, 512, nullptr, 5184);
    } else {
        // segmented fallback (round-8 proven path)
        bf16* wtm[9];
        {
            bf16* wp = wtmS;
            for (int i = 0; i < 9; ++i) { wtm[i] = wp; wp += (size_t)512 * Km[i]; }
        }
        wprep_mid_all<<<dim3(162, 16), dim3(32, 8), 0, stream>>>(W_mid, wtm[0]);
        f2b_pad<<<(int)(M * 8 / 256), 256, 0, stream>>>(x, xA);
        init_mid<<<(int)(M * 512 / 256), 256, 0, stream>>>(mid, b_mid);

        bf16* bufs[2] = {xA, xB};
        for (int L = 0; L < 8; ++L) {
            bf16* xin = bufs[L & 1];
            bf16* xout = bufs[(L + 1) & 1];
            const float* bo = (const float*)d_in[7 + 6 * L];
            mgemm<0><<<dim3(256, 1), 256, 0, stream>>>(
                xin, S[L], nullptr, 0, 9999,
                wsh[L], biassh + L * 128, (float*)hbuf, 64, sbuf, Kh[L]);
            knn_kernel<<<(int)(M / 4), 256, 0, stream>>>(sbuf, idxb, wgtb);
            gather_kernel<<<(int)(M / 4), 256, 0, stream>>>(
                hbuf, idxb, wgtb, xin, S[L], fi[L], (L == 0) ? 56 : 0);
            mgemm<2><<<dim3(256, 4), 256, 0, stream>>>(
                xin, S[L], nullptr, 0, 9999,
                wtm[L], nullptr, mid, 512, nullptr, Km[L]);
            mgemm<1><<<dim3(256, fo[L] / 128), 256, 0, stream>>>(
                xin, S[L], nullptr, 0, 9999,
                wto[L], bo, (float*)xout, S[L + 1], nullptr, Ko[L]);
        }
        mgemm<2><<<dim3(256, 4), 256, 0, stream>>>(
            bufs[0], S[8], nullptr, 0, 9999,
            wtm[8], nullptr, mid, 512, nullptr, Km[8]);
    }

    pool_kernel<<<dim3(GB, 16), 256, 0, stream>>>(mid, pooled);
    head_kernel<<<GB, 128, 0, stream>>>(pooled, W_head, b_head, (float*)d_out);
}

// Round 11
// 1982.820 us; speedup vs baseline: 7.3358x; 1.0493x over previous
//
#include <hip/hip_runtime.h>
#include <hip/hip_bf16.h>
#include <math.h>

#define M_ROWS 32768   // B*P
#define GB 128         // graphs
#define GP 256         // points per graph

typedef __hip_bfloat16 bf16;
typedef __attribute__((ext_vector_type(8))) short short8;
typedef __attribute__((ext_vector_type(4))) float f32x4;

// ---------------------------------------------------------------------------
__global__ void diag_kernel(float* out, float v) { out[0] = v; }

// ---------------------------------------------------------------------------
// MFMA GEMM, m97 structure: global_load_lds(16B) staging, linear LDS, 2-barrier
// K-loop. BM=128, BN=128, BK=64, 256 threads = 4 waves (2x2), 16x16x32 bf16.
// A is split-region: K-tiles < splitTile read from A1 (lda1), else A2 (lda2).
// MODE 0: cols<64 -> hbuf bf16 [M,64]; cols 64..71 -> sbuf f32 [M,8]
// MODE 1: out bf16 [M,ldc], bias+relu
// MODE 2: out f32 [M,ldc] += (accumulate, no bias)
// MODE 3: out f32 [M,ldc] = v + bias (one-shot mid)
// ---------------------------------------------------------------------------
template<int MODE>
__global__ __launch_bounds__(256) void mgemm(
    const bf16* __restrict__ A1, int lda1,
    const bf16* __restrict__ A2, int lda2, int splitTile,
    const bf16* __restrict__ Wt,              // [N, K] bf16 (W^T) row-major
    const float* __restrict__ bias,           // [N] f32 (unused MODE2)
    float* __restrict__ out0, int ldc,
    float* __restrict__ out1,                 // MODE0: sbuf
    int K)
{
    __shared__ unsigned short Alds[128][64];
    __shared__ unsigned short Blds[128][64];
    const int tid = threadIdx.x;
    const int l = tid & 63;
    const int w = tid >> 6;
    const int wr = w >> 1, wc = w & 1;
    const int rowBase = blockIdx.x * 128;
    const int colBase = blockIdx.y * 128;

    const int lr = l >> 3;          // 0..7
    const int lc = (l & 7) * 8;     // 0..56
    const int arow = rowBase + w * 32 + lr;
    const bf16* A1b = A1 + (size_t)arow * lda1 + lc;
    const bf16* A2b = A2 ? (A2 + (size_t)arow * lda2 + lc) : A1b;
    const bf16* Bb  = Wt + (size_t)(colBase + w * 32 + lr) * K + lc;

    f32x4 acc[4][4];
    #pragma unroll
    for (int m = 0; m < 4; ++m)
        #pragma unroll
        for (int n = 0; n < 4; ++n)
            acc[m][n] = (f32x4){0.f, 0.f, 0.f, 0.f};

    const int nt = K >> 6;
    for (int t = 0; t < nt; ++t) {
        const bf16* bp; int ldsel; int ko;
        if (t < splitTile) { bp = A1b; ldsel = lda1; ko = t << 6; }
        else               { bp = A2b; ldsel = lda2; ko = (t - splitTile) << 6; }
        const int kb = t << 6;
        __syncthreads();
        #pragma unroll
        for (int j = 0; j < 4; ++j) {
            __builtin_amdgcn_global_load_lds(
                (const __attribute__((address_space(1))) void*)(bp + (size_t)(j * 8) * ldsel + ko),
                (__attribute__((address_space(3))) void*)&Alds[w * 32 + j * 8][0],
                16, 0, 0);
            __builtin_amdgcn_global_load_lds(
                (const __attribute__((address_space(1))) void*)(Bb + (size_t)(j * 8) * K + kb),
                (__attribute__((address_space(3))) void*)&Blds[w * 32 + j * 8][0],
                16, 0, 0);
        }
        __syncthreads();
        #pragma unroll
        for (int kk = 0; kk < 2; ++kk) {
            const int co = kk * 32 + (l >> 4) * 8;
            short8 a[4], b[4];
            #pragma unroll
            for (int m = 0; m < 4; ++m)
                a[m] = *(const short8*)&Alds[wr * 64 + m * 16 + (l & 15)][co];
            #pragma unroll
            for (int n = 0; n < 4; ++n)
                b[n] = *(const short8*)&Blds[wc * 64 + n * 16 + (l & 15)][co];
            #pragma unroll
            for (int m = 0; m < 4; ++m)
                #pragma unroll
                for (int n = 0; n < 4; ++n)
                    acc[m][n] = __builtin_amdgcn_mfma_f32_16x16x32_bf16(
                        a[m], b[n], acc[m][n], 0, 0, 0);
        }
    }

    // epilogue: C/D layout col=lane&15, row=(lane>>4)*4+reg  [m89/m91]
    const int r0 = rowBase + wr * 64 + (l >> 4) * 4;
    const int c0 = colBase + wc * 64 + (l & 15);
    #pragma unroll
    for (int m = 0; m < 4; ++m) {
        #pragma unroll
        for (int n = 0; n < 4; ++n) {
            const int col = c0 + n * 16;
            const float bv = (MODE == 2) ? 0.f : bias[col];
            #pragma unroll
            for (int g = 0; g < 4; ++g) {
                const int row = r0 + m * 16 + g;
                float v = acc[m][n][g] + bv;
                if (MODE == 0) {
                    if (col < 64)
                        ((bf16*)out0)[(size_t)row * 64 + col] = __float2bfloat16(v);
                    else if (col < 72)
                        out1[(size_t)row * 8 + (col - 64)] = v;
                } else if (MODE == 1) {
                    ((bf16*)out0)[(size_t)row * ldc + col] =
                        __float2bfloat16(fmaxf(v, 0.f));
                } else if (MODE == 2) {
                    out0[(size_t)row * ldc + col] += v;
                } else {
                    out0[(size_t)row * ldc + col] = v;
                }
            }
        }
    }
}

// ---------------------------------------------------------------------------
// Fused Wo prep for all 8 layers. grid (36, 32, 8); guards trim.
// Wt[n,k]: k<fiReal -> W row k; fiPad<=k<fiPad+128 -> W row k-fiPad+fiReal.
// ---------------------------------------------------------------------------
struct WoArgs { const float* Wo[8]; };
__global__ __launch_bounds__(256) void wprep_t_all(
    WoArgs a, bf16* __restrict__ wtoBase, int bigFlag)
{
    const int fi_[8]   = {8, 256, 256, 512, 512, 512, 1024, 1024};
    const int fip_[8]  = {64, 256, 256, 512, 512, 512, 1024, 1024};
    const int fo_[8]   = {256, 256, 512, 512, 512, 1024, 1024, 1024};
    const int Ko_[8]   = {192, 384, 384, 640, 640, 640, 1152, 1152};
    const size_t ofs_[8] = {0, 49152, 147456, 344064, 671744, 999424,
                            1654784, 2834432};
    const int L = blockIdx.z;
    const int Kpad = Ko_[L], N = fo_[L];
    const int k_t = blockIdx.x * 32, n_t = blockIdx.y * 32;
    if (k_t >= Kpad || n_t >= N) return;
    const int fiReal = fi_[L];
    const int fiPad = bigFlag ? fip_[L] : fi_[L];
    const float* W = a.Wo[L];
    bf16* Wt = wtoBase + ofs_[L];

    __shared__ float tl[32][33];
    const int tx = threadIdx.x, ty = threadIdx.y;
    #pragma unroll
    for (int j = 0; j < 4; ++j) {
        int k = k_t + ty + j * 8;
        int s = (k < fiReal) ? k : ((k >= fiPad) ? (k - fiPad + fiReal) : -1);
        float v = 0.f;
        if (s >= 0 && s < fiReal + 128) v = W[(size_t)s * N + n_t + tx];
        tl[ty + j * 8][tx] = v;
    }
    __syncthreads();
    #pragma unroll
    for (int j = 0; j < 4; ++j) {
        int n = n_t + ty + j * 8;
        Wt[(size_t)n * Kpad + k_t + tx] = __float2bfloat16(tl[tx][ty + j * 8]);
    }
}

// ---------------------------------------------------------------------------
// Fused W_sh prep for all 8 layers. grid (4, 128, 8).
// rows 0..63 = Wh^T; 64..67 = hi(Ws^T); 68..71 = lo(Ws^T); rest 0.
// ---------------------------------------------------------------------------
struct ShArgs { const float* Wh[8]; const float* Ws[8]; };
__global__ __launch_bounds__(256) void wprep_sh_all(
    ShArgs a, bf16* __restrict__ wshBase)
{
    const int fi_[8] = {8, 256, 256, 512, 512, 512, 1024, 1024};
    const int Kh_[8] = {64, 256, 256, 512, 512, 512, 1024, 1024};
    const size_t ofs_[8] = {0, 8192, 40960, 73728, 139264, 204800,
                            270336, 401408};
    const int L = blockIdx.z;
    const int Khpad = Kh_[L];
    const int k = blockIdx.x * 256 + threadIdx.x;
    if (k >= Khpad) return;
    const int n = blockIdx.y;
    const int fi = fi_[L];
    float v = 0.f;
    if (k < fi) {
        if (n < 64) v = a.Wh[L][(size_t)k * 64 + n];
        else if (n < 68) {
            v = __bfloat162float(__float2bfloat16(a.Ws[L][(size_t)k * 4 + (n - 64)]));
        } else if (n < 72) {
            float wv = a.Ws[L][(size_t)k * 4 + (n - 68)];
            float hi = __bfloat162float(__float2bfloat16(wv));
            v = wv - hi;
        }
    }
    (wshBase + ofs_[L])[(size_t)n * Khpad + k] = __float2bfloat16(v);
}

// ---------------------------------------------------------------------------
// Segmented W_mid prep (small path). grid (162,16).
// ---------------------------------------------------------------------------
__global__ __launch_bounds__(256) void wprep_mid_all(
    const float* __restrict__ W_mid, bf16* __restrict__ wtm0)
{
    const int segBlkStart[10] = {0, 2, 10, 18, 34, 50, 66, 98, 130, 162};
    const int segKm[9]   = {64, 256, 256, 512, 512, 512, 1024, 1024, 1024};
    const int segKr[9]   = {8, 256, 256, 512, 512, 512, 1024, 1024, 1024};
    const int segMrow[9] = {0, 8, 264, 520, 1032, 1544, 2056, 3080, 4104};
    const int segWOff[9] = {0, 32768, 163840, 294912, 557056, 819200,
                            1081344, 1605632, 2129920};
    __shared__ float tl[32][33];
    int bx = blockIdx.x;
    int seg = 0;
    while (bx >= segBlkStart[seg + 1]) ++seg;
    const int kb = bx - segBlkStart[seg];
    const float* W = W_mid + (size_t)segMrow[seg] * 512;
    bf16* Wt = wtm0 + segWOff[seg];
    const int K = segKr[seg], Kpad = segKm[seg];
    const int tx = threadIdx.x, ty = threadIdx.y;
    const int k_t = kb * 32, n_t = blockIdx.y * 32;
    #pragma unroll
    for (int j = 0; j < 4; ++j) {
        int k = k_t + ty + j * 8;
        tl[ty + j * 8][tx] = (k < K) ? W[(size_t)k * 512 + n_t + tx] : 0.f;
    }
    __syncthreads();
    #pragma unroll
    for (int j = 0; j < 4; ++j) {
        int n = n_t + ty + j * 8;
        Wt[(size_t)n * Kpad + k_t + tx] = __float2bfloat16(tl[tx][ty + j * 8]);
    }
}

// ---------------------------------------------------------------------------
// One-shot W_mid prep (big path): Wt [512, 5184] bf16. grid (162,16).
// ---------------------------------------------------------------------------
__global__ __launch_bounds__(256) void wprep_mid_big(
    const float* __restrict__ W_mid, bf16* __restrict__ Wt)
{
    const int off_[9]  = {0, 64, 320, 576, 1088, 1600, 2112, 3136, 4160};
    const int size_[9] = {8, 256, 256, 512, 512, 512, 1024, 1024, 1024};
    const int mrow_[9] = {0, 8, 264, 520, 1032, 1544, 2056, 3080, 4104};
    __shared__ float tl[32][33];
    const int tx = threadIdx.x, ty = threadIdx.y;
    const int k_t = blockIdx.x * 32, n_t = blockIdx.y * 32;
    #pragma unroll
    for (int j = 0; j < 4; ++j) {
        int k = k_t + ty + j * 8;
        int s = -1;
        #pragma unroll
        for (int g = 0; g < 9; ++g)
            if (k >= off_[g] && k < off_[g] + size_[g]) s = mrow_[g] + (k - off_[g]);
        tl[ty + j * 8][tx] = (s >= 0) ? W_mid[(size_t)s * 512 + n_t + tx] : 0.f;
    }
    __syncthreads();
    #pragma unroll
    for (int j = 0; j < 4; ++j) {
        int n = n_t + ty + j * 8;
        Wt[(size_t)n * 5184 + k_t + tx] = __float2bfloat16(tl[tx][ty + j * 8]);
    }
}

struct BiasArgs { const float* bh[8]; const float* bs[8]; };
__global__ __launch_bounds__(128) void bias_build_all(
    BiasArgs a, float* __restrict__ out)
{
    const int L = blockIdx.x, t = threadIdx.x;
    out[L * 128 + t] = (t < 64) ? a.bh[L][t] : (t < 68 ? a.bs[L][t - 64] : 0.f);
}

// ---------------------------------------------------------------------------
__global__ __launch_bounds__(256) void f2b_pad(const float* __restrict__ in,
                                               bf16* __restrict__ out)
{
    int i = blockIdx.x * 256 + threadIdx.x;
    int row = i >> 3, c = i & 7;
    out[(size_t)row * 192 + c] = __float2bfloat16(in[i]);
}

__global__ __launch_bounds__(256) void f2b_big(const float* __restrict__ in,
                                               bf16* __restrict__ feat)
{
    int i = blockIdx.x * 256 + threadIdx.x;   // M*64
    int row = i >> 6, c = i & 63;
    feat[(size_t)row * 5184 + c] =
        __float2bfloat16(c < 8 ? in[row * 8 + c] : 0.f);
}

// ---------------------------------------------------------------------------
// Wave-64 integer min reduce via DPP (VALU pipe), broadcast via readlane(63).
// Valid for non-negative float bit patterns.
// ---------------------------------------------------------------------------
__device__ __forceinline__ int wave_imin_bcast(int x)
{
    int y;
    y = __builtin_amdgcn_update_dpp(x, x, 0x111, 0xf, 0xf, false); x = y < x ? y : x;
    y = __builtin_amdgcn_update_dpp(x, x, 0x112, 0xf, 0xf, false); x = y < x ? y : x;
    y = __builtin_amdgcn_update_dpp(x, x, 0x114, 0xf, 0xf, false); x = y < x ? y : x;
    y = __builtin_amdgcn_update_dpp(x, x, 0x118, 0xf, 0xf, false); x = y < x ? y : x;
    y = __builtin_amdgcn_update_dpp(x, x, 0x142, 0xf, 0xf, false); x = y < x ? y : x;
    y = __builtin_amdgcn_update_dpp(x, x, 0x143, 0xf, 0xf, false); x = y < x ? y : x;
    return __builtin_amdgcn_readlane(x, 63);
}

// ---------------------------------------------------------------------------
// Fused kNN + gather. 4 waves/block = 4 points; grid M/4.
// Phase 1 (per wave): top-20 via DPP-min extraction (named regs, no scratch).
// Handoff: lanes 0..19 write (q, w=exp(-10d)) to per-wave LDS.
// Phase 2 (per wave): aggregate its point: lane=feature f (64), k=0..19
// LDS-broadcast neighbor reads. Writes [mean|max] into activation buffer.
// ---------------------------------------------------------------------------
__global__ __launch_bounds__(256) void knng_kernel(
    const float* __restrict__ sbuf,   // [B*P, 8] (hi/lo split)
    const bf16* __restrict__ h,       // [B*P, 64]
    bf16* __restrict__ xtgt, int stride, int fiL, int padN)
{
    __shared__ float ss[GP][5];
    __shared__ int   qsh[4][20];
    __shared__ float wvs[4][20];
    const int t = threadIdx.x;
    const int b = blockIdx.x >> 6;
    {
        const float4 v1 = ((const float4*)(sbuf + ((size_t)b * GP + t) * 8))[0];
        const float4 v2 = ((const float4*)(sbuf + ((size_t)b * GP + t) * 8))[1];
        float ax = v1.x + v2.x, ay = v1.y + v2.y,
              az = v1.z + v2.z, aw = v1.w + v2.w;
        ss[t][0] = ax; ss[t][1] = ay; ss[t][2] = az; ss[t][3] = aw;
        ss[t][4] = ax * ax + ay * ay + az * az + aw * aw;
    }
    __syncthreads();

    const int w = t >> 6, l = t & 63;
    const int pt = blockIdx.x * 4 + w;          // global point id
    const int p = pt & 255;                     // local point id
    const float px = ss[p][0], py = ss[p][1], pz = ss[p][2], pq = ss[p][3];
    const float psq = ss[p][4];

    float d0, d1, d2, d3; int q0, q1, q2, q3;
    #define KNN_DIST(DD, QQ, J) { \
        const int q_ = l + (J) * 64; \
        float dot_ = px * ss[q_][0] + py * ss[q_][1] \
                   + pz * ss[q_][2] + pq * ss[q_][3]; \
        DD = fmaxf(psq + ss[q_][4] - 2.f * dot_, 0.f); QQ = q_; }
    KNN_DIST(d0, q0, 0) KNN_DIST(d1, q1, 1)
    KNN_DIST(d2, q2, 2) KNN_DIST(d3, q3, 3)
    #undef KNN_DIST
    #define KNN_CE(DA, DB, QA, QB) { \
        if (DA > DB) { float td = DA; DA = DB; DB = td; \
                       int tq = QA; QA = QB; QB = tq; } }
    KNN_CE(d0, d1, q0, q1) KNN_CE(d2, d3, q2, q3)
    KNN_CE(d0, d2, q0, q2) KNN_CE(d1, d3, q1, q3)
    KNN_CE(d1, d2, q1, q2)
    #undef KNN_CE

    float outd = 0.f; int outq = 0;
    #pragma unroll
    for (int k = 0; k < 20; ++k) {
        const int mb = wave_imin_bcast(__float_as_int(d0));
        unsigned long long msk = __ballot(__float_as_int(d0) == mb);
        const int winner = __ffsll((long long)msk) - 1;
        const int qwin = __builtin_amdgcn_readlane(q0, winner);
        if (l == k) { outd = __int_as_float(mb); outq = qwin; }
        const bool pop = (l == winner);
        d0 = pop ? d1 : d0; q0 = pop ? q1 : q0;
        d1 = pop ? d2 : d1; q1 = pop ? q2 : q1;
        d2 = pop ? d3 : d2; q2 = pop ? q3 : q2;
        d3 = pop ? 3.402823466e38f : d3;
    }
    if (l < 20) {
        qsh[w][l] = outq;
        wvs[w][l] = expf(-10.f * outd);
    }
    __syncthreads();

    // gather: lane = feature, LDS same-address broadcast for (q, w)
    float sum = 0.f, mx = -3.402823466e38f;
    #pragma unroll 4
    for (int k = 0; k < 20; ++k) {
        const int q = qsh[w][k];
        const float wv = wvs[w][k];
        float val = __bfloat162float(h[(((size_t)b << 8) + q) * 64 + l]) * wv;
        sum += val;
        mx = fmaxf(mx, val);
    }
    bf16* out = xtgt + (size_t)pt * stride + fiL;
    out[l] = __float2bfloat16(sum * (1.f / 20.f));
    out[64 + l] = __float2bfloat16(mx);
    if (l < padN) out[128 + l] = __float2bfloat16(0.f);
}

// ---------------------------------------------------------------------------
__global__ __launch_bounds__(256) void init_mid(float* __restrict__ mid,
                                                const float* __restrict__ b_mid)
{
    size_t i = (size_t)blockIdx.x * 256 + threadIdx.x;
    mid[i] = b_mid[i & 511];
}

// ---------------------------------------------------------------------------
// Multi-pool (min,max,mean,sum,std,median-lower); median via bitonic sort.
// ---------------------------------------------------------------------------
__global__ __launch_bounds__(256) void pool_kernel(
    const float* __restrict__ mid, float* __restrict__ pooled)
{
    __shared__ float tile[GP][33];
    __shared__ float rbuf[256];
    const int b = blockIdx.x;
    const int c0 = blockIdx.y * 32;
    const int t = threadIdx.x;

    #pragma unroll 8
    for (int l = 0; l < 32; ++l) {
        int lin = l * 256 + t;
        int row = lin >> 5;
        int col = lin & 31;
        tile[row][col] = mid[((size_t)b * GP + row) * 512 + c0 + col];
    }
    __syncthreads();

    const int col = t & 31, g = t >> 5;
    float mn = 3.402823466e38f, mx = -3.402823466e38f, sm = 0.f, s2 = 0.f;
    for (int r = g * 32; r < g * 32 + 32; ++r) {
        float v = tile[r][col];
        mn = fminf(mn, v); mx = fmaxf(mx, v); sm += v; s2 += v * v;
    }
    float* outb = pooled + (size_t)b * 3072 + c0;

    rbuf[t] = mn; __syncthreads();
    if (t < 32) {
        float v = rbuf[t];
        #pragma unroll
        for (int k = 1; k < 8; ++k) v = fminf(v, rbuf[t + 32 * k]);
        outb[0 * 512 + t] = v;
    }
    __syncthreads();
    rbuf[t] = mx; __syncthreads();
    if (t < 32) {
        float v = rbuf[t];
        #pragma unroll
        for (int k = 1; k < 8; ++k) v = fmaxf(v, rbuf[t + 32 * k]);
        outb[1 * 512 + t] = v;
    }
    __syncthreads();
    rbuf[t] = sm; __syncthreads();
    float meanv = 0.f;
    if (t < 32) {
        float v = 0.f;
        #pragma unroll
        for (int k = 0; k < 8; ++k) v += rbuf[t + 32 * k];
        meanv = v * (1.f / 256.f);
        outb[2 * 512 + t] = meanv;
        outb[3 * 512 + t] = v;
    }
    __syncthreads();
    rbuf[t] = s2; __syncthreads();
    if (t < 32) {
        float v = 0.f;
        #pragma unroll
        for (int k = 0; k < 8; ++k) v += rbuf[t + 32 * k];
        float var = v * (1.f / 256.f) - meanv * meanv;
        outb[4 * 512 + t] = sqrtf(fmaxf(var, 0.f) + 1e-5f);
    }

    for (int size = 2; size <= 256; size <<= 1) {
        for (int stride = size >> 1; stride > 0; stride >>= 1) {
            __syncthreads();
            #pragma unroll
            for (int it = 0; it < 16; ++it) {
                int task = it * 256 + t;
                int c = task & 31;
                int pp = task >> 5;
                int i = 2 * pp - (pp & (stride - 1));
                int j = i + stride;
                bool up = ((i & size) == 0);
                float va = tile[i][c], vb = tile[j][c];
                bool sw = up ? (va > vb) : (va < vb);
                if (sw) { tile[i][c] = vb; tile[j][c] = va; }
            }
        }
    }
    __syncthreads();
    if (t < 32) outb[5 * 512 + t] = tile[127][t];
}

// ---------------------------------------------------------------------------
__global__ __launch_bounds__(128) void head_kernel(
    const float* __restrict__ pooled, const float* __restrict__ Wh,
    const float* __restrict__ bh, float* __restrict__ out)
{
    __shared__ float sh[3072];
    const int b = blockIdx.x, t = threadIdx.x;
    for (int l = t; l < 3072; l += 128) sh[l] = pooled[(size_t)b * 3072 + l];
    __syncthreads();
    float acc = bh[t];
    for (int k = 0; k < 3072; ++k) acc += sh[k] * Wh[(size_t)k * 128 + t];
    out[(size_t)b * 128 + t] = acc;
}

// ---------------------------------------------------------------------------
extern "C" void kernel_launch(void* const* d_in, const int* in_sizes, int n_in,
                              void* d_out, int out_size, void* d_ws, size_t ws_size,
                              hipStream_t stream)
{
    const int fi[8]  = {8, 256, 256, 512, 512, 512, 1024, 1024};
    const int fip[8] = {64, 256, 256, 512, 512, 512, 1024, 1024};
    const int fo[8]  = {256, 256, 512, 512, 512, 1024, 1024, 1024};
    const int Kh[8]  = {64, 256, 256, 512, 512, 512, 1024, 1024};
    const int Ko[8]  = {192, 384, 384, 640, 640, 640, 1152, 1152};
    const int Km[9]  = {64, 256, 256, 512, 512, 512, 1024, 1024, 1024};
    const int off[9] = {0, 64, 320, 576, 1088, 1600, 2112, 3136, 4160};
    const int S[9]   = {192, 384, 384, 640, 640, 640, 1152, 1152, 1024};

    const float* x      = (const float*)d_in[0];
    const float* W_mid  = (const float*)d_in[50];
    const float* b_mid  = (const float*)d_in[51];
    const float* W_head = (const float*)d_in[52];
    const float* b_head = (const float*)d_in[53];

    const size_t M = M_ROWS;

    // -------- common buffers --------
    char* p = (char*)d_ws;
    float* mid    = (float*)p; p += M * 512 * 4;
    float* sbuf   = (float*)p; p += M * 8 * 4;
    float* pooled = (float*)p; p += 128 * 3072 * 4;
    float* biassh = (float*)p; p += 8 * 128 * 4;
    bf16*  hbuf   = (bf16*)p;  p += M * 64 * 2;

    // -------- big-path layout --------
    char* pb = p;
    bf16* aggb = (bf16*)pb; pb += M * 128 * 2;
    bf16* feat = (bf16*)pb; pb += M * 5184 * 2;
    bf16* wshB = (bf16*)pb; pb += (size_t)532480 * 2;    // sum 128*Kh
    bf16* wtoB = (bf16*)pb; pb += (size_t)4014080 * 2;   // sum fo*Ko
    bf16* wtmB = (bf16*)pb; pb += (size_t)512 * 5184 * 2;
    const size_t neededBig = (size_t)(pb - (char*)d_ws);

    // -------- small-path layout --------
    char* ps = p;
    bf16* xA = (bf16*)ps; ps += M * 1152 * 2;
    bf16* xB = (bf16*)ps; ps += M * 1152 * 2;
    bf16* wshS = (bf16*)ps; ps += (size_t)532480 * 2;
    bf16* wtoS = (bf16*)ps; ps += (size_t)4014080 * 2;
    bf16* wtmS = (bf16*)ps; ps += (size_t)512 * 5184 * 2; // sum 512*Km = 512*5184
    const size_t neededSmall = (size_t)(ps - (char*)d_ws);

    if (ws_size < neededSmall) {
        diag_kernel<<<1, 1, 0, stream>>>((float*)d_out, (float)ws_size);
        return;
    }
    const bool big = (ws_size >= neededBig);

    bf16* wshBase = big ? wshB : wshS;
    bf16* wtoBase = big ? wtoB : wtoS;
    const size_t wshOfs[8] = {0, 8192, 40960, 73728, 139264, 204800,
                              270336, 401408};
    const size_t wtoOfs[8] = {0, 49152, 147456, 344064, 671744, 999424,
                              1654784, 2834432};

    // -------- weight prep (fused) --------
    BiasArgs ba; ShArgs sa; WoArgs wa;
    for (int L = 0; L < 8; ++L) {
        sa.Ws[L] = (const float*)d_in[2 + 6 * L];
        ba.bs[L] = (const float*)d_in[3 + 6 * L];
        sa.Wh[L] = (const float*)d_in[4 + 6 * L];
        ba.bh[L] = (const float*)d_in[5 + 6 * L];
        wa.Wo[L] = (const float*)d_in[6 + 6 * L];
    }
    wprep_sh_all<<<dim3(4, 128, 8), 256, 0, stream>>>(sa, wshBase);
    wprep_t_all<<<dim3(36, 32, 8), dim3(32, 8), 0, stream>>>(
        wa, wtoBase, big ? 1 : 0);
    bias_build_all<<<8, 128, 0, stream>>>(ba, biassh);

    if (big) {
        wprep_mid_big<<<dim3(162, 16), dim3(32, 8), 0, stream>>>(W_mid, wtmB);
        f2b_big<<<(int)(M * 64 / 256), 256, 0, stream>>>(x, feat);

        for (int L = 0; L < 8; ++L) {
            const float* bo = (const float*)d_in[7 + 6 * L];
            mgemm<0><<<dim3(256, 1), 256, 0, stream>>>(
                feat + off[L], 5184, nullptr, 0, 9999,
                wshBase + wshOfs[L], biassh + L * 128, (float*)hbuf, 64, sbuf, Kh[L]);
            knng_kernel<<<(int)(M / 4), 256, 0, stream>>>(
                sbuf, hbuf, aggb, 128, 0, 0);
            mgemm<1><<<dim3(256, fo[L] / 128), 256, 0, stream>>>(
                feat + off[L], 5184, aggb, 128, fip[L] >> 6,
                wtoBase + wtoOfs[L], bo, (float*)(feat + off[L + 1]), 5184,
                nullptr, Ko[L]);
        }
        mgemm<3><<<dim3(256, 4), 256, 0, stream>>>(
            feat, 5184, nullptr, 0, 9999,
            wtmB, b_mid, mid, 512, nullptr, 5184);
    } else {
        bf16* wtm[9];
        {
            bf16* wp = wtmS;
            for (int i = 0; i < 9; ++i) { wtm[i] = wp; wp += (size_t)512 * Km[i]; }
        }
        wprep_mid_all<<<dim3(162, 16), dim3(32, 8), 0, stream>>>(W_mid, wtm[0]);
        f2b_pad<<<(int)(M * 8 / 256), 256, 0, stream>>>(x, xA);
        init_mid<<<(int)(M * 512 / 256), 256, 0, stream>>>(mid, b_mid);

        bf16* bufs[2] = {xA, xB};
        for (int L = 0; L < 8; ++L) {
            bf16* xin = bufs[L & 1];
            bf16* xout = bufs[(L + 1) & 1];
            const float* bo = (const float*)d_in[7 + 6 * L];
            mgemm<0><<<dim3(256, 1), 256, 0, stream>>>(
                xin, S[L], nullptr, 0, 9999,
                wshBase + wshOfs[L], biassh + L * 128, (float*)hbuf, 64, sbuf, Kh[L]);
            knng_kernel<<<(int)(M / 4), 256, 0, stream>>>(
                sbuf, hbuf, xin, S[L], fi[L], (L == 0) ? 56 : 0);
            mgemm<2><<<dim3(256, 4), 256, 0, stream>>>(
                xin, S[L], nullptr, 0, 9999,
                wtm[L], nullptr, mid, 512, nullptr, Km[L]);
            mgemm<1><<<dim3(256, fo[L] / 128), 256, 0, stream>>>(
                xin, S[L], nullptr, 0, 9999,
                wtoBase + wtoOfs[L], bo, (float*)xout, S[L + 1], nullptr, Ko[L]);
        }
        mgemm<2><<<dim3(256, 4), 256, 0, stream>>>(
            bufs[0], S[8], nullptr, 0, 9999,
            wtm[8], nullptr, mid, 512, nullptr, Km[8]);
    }

    pool_kernel<<<dim3(GB, 16), 256, 0, stream>>>(mid, pooled);
    head_kernel<<<GB, 128, 0, stream>>>(pooled, W_head, b_head, (float*)d_out);
}